// Round 5
// baseline (538.456 us; speedup 1.0000x reference)
//
#include <hip/hip_runtime.h>

// Problem constants: B=4, T=2048, D=1024, H=16, HD=64
// Math (certified r6): torch convention x@W.T+b, rotate-half RoPE pos=t+1,
// causal softmax(QK^T/8)V, O-proj. Output f32 [B,T,D].
// R5: consolidation. conv x5 -> 1; QKV gemms x3 -> 1 launch (sel per block)
// with RoPE fused into the epilogue (rotation on f32 acc, pre-rounding);
// bijective XCD swizzle on both GEMM grids. attn unchanged (verified R4).
#define BB 4
#define TT 2048
#define DD 1024
#define HH 16
#define HD 64

typedef __attribute__((ext_vector_type(8))) _Float16 f16x8;
typedef __attribute__((ext_vector_type(4))) float f32x4;
typedef __attribute__((ext_vector_type(2))) unsigned int u32x2;
typedef __attribute__((ext_vector_type(4))) unsigned int u32x4;

__device__ __forceinline__ float h2f(unsigned short u) {
    return (float)__builtin_bit_cast(_Float16, u);
}
__device__ __forceinline__ unsigned short f2h(float f) {
    return __builtin_bit_cast(unsigned short, (_Float16)f);
}
__device__ __forceinline__ unsigned int pkrtz(float a, float b) {
    return __builtin_bit_cast(unsigned int, __builtin_amdgcn_cvt_pkrtz(a, b));
}

// ---------------------------------------------------------------------------
// Fused f32 -> f16 convert for x + Wq + Wk + Wv + Wo (one launch).
// Grid 12288: blocks [0,8192) -> x (2097152 float4), then 1024 blocks per W.
// W outputs land contiguous (wq|wk|wv|wo) so QKV gemm can index by sel.
// ---------------------------------------------------------------------------
__global__ __launch_bounds__(256) void conv_all(
    const float4* __restrict__ x,
    const float4* __restrict__ Wq, const float4* __restrict__ Wk,
    const float4* __restrict__ Wv, const float4* __restrict__ Wo,
    ushort4* __restrict__ xh, ushort4* __restrict__ wh)
{
    int vi = blockIdx.x * 256 + threadIdx.x;
    if (vi < 2097152) {
        float4 v = x[vi];
        xh[vi] = (ushort4){ f2h(v.x), f2h(v.y), f2h(v.z), f2h(v.w) };
    } else {
        int u = vi - 2097152;               // [0, 1048576)
        int w = u >> 18;                    // 0..3 (uniform per block)
        const float4* src = (w == 0) ? Wq : (w == 1) ? Wk : (w == 2) ? Wv : Wo;
        float4 v = src[u & 262143];
        wh[u] = (ushort4){ f2h(v.x), f2h(v.y), f2h(v.z), f2h(v.w) };
    }
}

// ---------------------------------------------------------------------------
// Fused QKV MFMA GEMM + RoPE epilogue.
// Grid 1536 (1D, XCD-swizzled): sel = which projection (q/k/v), 8 j-blocks
// x 64 n-blocks per sel. Tile 128x128, BK=64, 4 waves, 16x16x32 f16 MFMA,
// 16B XOR-swizzled LDS (verified R2 structure).
// Epilogue: bias add; for q/k apply rotate-half RoPE on the f32 acc using
// frag pairs (nj, nj+2) = cols (dd, dd+32); scatter f16 [B,H,T,64].
// ---------------------------------------------------------------------------
__global__ __launch_bounds__(256) void gemm_qkv(
    const unsigned short* __restrict__ A,      // x_h [8192][1024]
    const unsigned short* __restrict__ Wall,   // wq|wk|wv f16 [3][1024][1024]
    const float* __restrict__ bq, const float* __restrict__ bk,
    const float* __restrict__ bv,
    unsigned short* __restrict__ qkv)          // q|k|v f16 [3][B,H,T,64]
{
    __shared__ __align__(16) unsigned short As[128 * 64];
    __shared__ __align__(16) unsigned short Ws[128 * 64];

    // bijective XCD swizzle: 1536 blocks -> 192 contiguous per XCD
    int bid = blockIdx.x;
    int swz = (bid & 7) * 192 + (bid >> 3);
    int bx = swz % 24, by = swz / 24;
    const int sel = bx >> 3;                   // 0=q 1=k 2=v
    const int jb = bx & 7;
    const int n0 = by * 128;
    const int j0 = jb * 128;

    const unsigned short* W = Wall + (size_t)sel * 1048576;
    const float* bias = (sel == 0) ? bq : (sel == 1) ? bk : bv;
    unsigned short* outp = qkv + (size_t)sel * (BB * HH * TT * HD);

    const int tid = threadIdx.x;
    const int w = tid >> 6, lane = tid & 63;
    const int l15 = lane & 15, g = lane >> 4;
    const int wr = w >> 1, wc = w & 1;

    f32x4 acc[4][4];
#pragma unroll
    for (int mi = 0; mi < 4; mi++)
#pragma unroll
        for (int nj = 0; nj < 4; nj++) acc[mi][nj] = (f32x4){0.f, 0.f, 0.f, 0.f};

    u32x4 pa[4], pb[4];
#define LOADREGS(KS)                                                             \
    {                                                                            \
        _Pragma("unroll")                                                        \
        for (int it = 0; it < 4; it++) {                                         \
            int ci = tid + it * 256;                                             \
            int r = ci >> 3, p = ci & 7;                                         \
            pa[it] = *(const u32x4*)(A + (size_t)(n0 + r) * 1024 + (KS) + p * 8);\
            pb[it] = *(const u32x4*)(W + (size_t)(j0 + r) * 1024 + (KS) + p * 8);\
        }                                                                        \
    }

    LOADREGS(0)

    for (int ks = 0; ks < 1024; ks += 64) {
        __syncthreads();
#pragma unroll
        for (int it = 0; it < 4; it++) {
            int ci = tid + it * 256;
            int r = ci >> 3, p = ci & 7;
            int d = r * 64 + ((p ^ (r & 7)) << 3);
            *(u32x4*)(As + d) = pa[it];
            *(u32x4*)(Ws + d) = pb[it];
        }
        __syncthreads();
        if (ks + 64 < 1024) LOADREGS(ks + 64)

#pragma unroll
        for (int c = 0; c < 2; c++) {
            f16x8 af[4], bf[4];
            const int q0c = c * 4 + (g >> 1);
            const int q1c = q0c + 2;
            const int off = (g & 1) << 2;
#pragma unroll
            for (int mi = 0; mi < 4; mi++) {
                int r = mi * 16 + l15;          // wr folded below via As base
                int rr = wr * 64 + r;
                int sw = rr & 7;
                const unsigned short* rp = As + rr * 64;
                u32x2 x0 = *(const u32x2*)(rp + ((q0c ^ sw) << 3) + off);
                u32x2 x1 = *(const u32x2*)(rp + ((q1c ^ sw) << 3) + off);
                u32x4 uu = {x0.x, x0.y, x1.x, x1.y};
                af[mi] = __builtin_bit_cast(f16x8, uu);
            }
#pragma unroll
            for (int nj = 0; nj < 4; nj++) {
                int rr = wc * 64 + nj * 16 + l15;
                int sw = rr & 7;
                const unsigned short* rp = Ws + rr * 64;
                u32x2 x0 = *(const u32x2*)(rp + ((q0c ^ sw) << 3) + off);
                u32x2 x1 = *(const u32x2*)(rp + ((q1c ^ sw) << 3) + off);
                u32x4 uu = {x0.x, x0.y, x1.x, x1.y};
                bf[nj] = __builtin_bit_cast(f16x8, uu);
            }
#pragma unroll
            for (int mi = 0; mi < 4; mi++)
#pragma unroll
                for (int nj = 0; nj < 4; nj++)
                    acc[mi][nj] = __builtin_amdgcn_mfma_f32_16x16x32_f16(
                        af[mi], bf[nj], acc[mi][nj], 0, 0, 0);
        }
    }
#undef LOADREGS

    // ---- epilogue ----
    float bb4[4];
#pragma unroll
    for (int nj = 0; nj < 4; nj++) bb4[nj] = bias[j0 + wc * 64 + nj * 16 + l15];
    const int hh = (j0 >> 6) + wc;             // head 0..15

    if (sel == 2) {
        // V: plain scatter
#pragma unroll
        for (int mi = 0; mi < 4; mi++)
#pragma unroll
            for (int r = 0; r < 4; r++) {
                int n = n0 + wr * 64 + mi * 16 + 4 * g + r;
                int b = n >> 11, t = n & (TT - 1);
                size_t rowbase = ((size_t)(b * HH + hh) * TT + t) << 6;
#pragma unroll
                for (int nj = 0; nj < 4; nj++) {
                    int dd = nj * 16 + l15;
                    outp[rowbase + dd] = f2h(acc[mi][nj][r] + bb4[nj]);
                }
            }
    } else {
        // Q/K: rotate-half RoPE on f32 acc. Pair (nj, nj+2) = (i, i+32),
        // i = nj*16 + l15; theta_i = 10000^(-i/32); pos = t+1.
        float th[2];
#pragma unroll
        for (int p = 0; p < 2; p++)
            th[p] = exp2f(-(float)(p * 16 + l15) * (13.287712379549449f / 32.0f));
#pragma unroll
        for (int mi = 0; mi < 4; mi++)
#pragma unroll
            for (int r = 0; r < 4; r++) {
                int n = n0 + wr * 64 + mi * 16 + 4 * g + r;
                int b = n >> 11, t = n & (TT - 1);
                size_t rowbase = ((size_t)(b * HH + hh) * TT + t) << 6;
#pragma unroll
                for (int p = 0; p < 2; p++) {
                    float x1 = acc[mi][p][r]     + bb4[p];
                    float x2 = acc[mi][p + 2][r] + bb4[p + 2];
                    float ang = (float)(t + 1) * th[p];
                    float s = sinf(ang), c = cosf(ang);
                    int i = p * 16 + l15;
                    outp[rowbase + i]      = f2h(x1 * c - x2 * s);
                    outp[rowbase + i + 32] = f2h(x2 * c + x1 * s);
                }
            }
    }
}

// ---------------------------------------------------------------------------
// MFMA f16 GEMM for O-projection (verified R2 structure + XCD swizzle).
// out[n,j] = sum_k A[n,k]*W[j,k] + bias[j], f32 flat output.
// ---------------------------------------------------------------------------
__global__ __launch_bounds__(256) void gemm_h(
    const unsigned short* __restrict__ A, const unsigned short* __restrict__ W,
    const float* __restrict__ bias, float* __restrict__ outp,
    int N, int K, int J)
{
    __shared__ __align__(16) unsigned short As[128 * 64];
    __shared__ __align__(16) unsigned short Ws[128 * 64];

    // bijective XCD swizzle over the flat grid (total must be %8==0)
    int total = gridDim.x * gridDim.y;
    int flat = blockIdx.y * gridDim.x + blockIdx.x;
    int swz = (flat & 7) * (total >> 3) + (flat >> 3);
    int bxi = swz % gridDim.x, byi = swz / gridDim.x;

    const int tid = threadIdx.x;
    const int w = tid >> 6, lane = tid & 63;
    const int l15 = lane & 15, g = lane >> 4;
    const int wr = w >> 1, wc = w & 1;
    const int n0 = byi * 128;
    const int j0 = bxi * 128;

    f32x4 acc[4][4];
#pragma unroll
    for (int mi = 0; mi < 4; mi++)
#pragma unroll
        for (int nj = 0; nj < 4; nj++) acc[mi][nj] = (f32x4){0.f, 0.f, 0.f, 0.f};

    u32x4 pa[4], pb[4];
#define LOADREGS(KS)                                                          \
    {                                                                         \
        _Pragma("unroll")                                                     \
        for (int it = 0; it < 4; it++) {                                      \
            int ci = tid + it * 256;                                          \
            int r = ci >> 3, p = ci & 7;                                      \
            pa[it] = *(const u32x4*)(A + (size_t)(n0 + r) * K + (KS) + p * 8);\
            pb[it] = *(const u32x4*)(W + (size_t)(j0 + r) * K + (KS) + p * 8);\
        }                                                                     \
    }

    LOADREGS(0)

    for (int ks = 0; ks < K; ks += 64) {
        __syncthreads();
#pragma unroll
        for (int it = 0; it < 4; it++) {
            int ci = tid + it * 256;
            int r = ci >> 3, p = ci & 7;
            int d = r * 64 + ((p ^ (r & 7)) << 3);
            *(u32x4*)(As + d) = pa[it];
            *(u32x4*)(Ws + d) = pb[it];
        }
        __syncthreads();
        if (ks + 64 < K) LOADREGS(ks + 64)

#pragma unroll
        for (int c = 0; c < 2; c++) {
            f16x8 af[4], bf[4];
            const int q0c = c * 4 + (g >> 1);
            const int q1c = q0c + 2;
            const int off = (g & 1) << 2;
#pragma unroll
            for (int mi = 0; mi < 4; mi++) {
                int r = wr * 64 + mi * 16 + l15;
                int sw = r & 7;
                const unsigned short* rp = As + r * 64;
                u32x2 x0 = *(const u32x2*)(rp + ((q0c ^ sw) << 3) + off);
                u32x2 x1 = *(const u32x2*)(rp + ((q1c ^ sw) << 3) + off);
                u32x4 uu = {x0.x, x0.y, x1.x, x1.y};
                af[mi] = __builtin_bit_cast(f16x8, uu);
            }
#pragma unroll
            for (int nj = 0; nj < 4; nj++) {
                int r = wc * 64 + nj * 16 + l15;
                int sw = r & 7;
                const unsigned short* rp = Ws + r * 64;
                u32x2 x0 = *(const u32x2*)(rp + ((q0c ^ sw) << 3) + off);
                u32x2 x1 = *(const u32x2*)(rp + ((q1c ^ sw) << 3) + off);
                u32x4 uu = {x0.x, x0.y, x1.x, x1.y};
                bf[nj] = __builtin_bit_cast(f16x8, uu);
            }
#pragma unroll
            for (int mi = 0; mi < 4; mi++)
#pragma unroll
                for (int nj = 0; nj < 4; nj++)
                    acc[mi][nj] = __builtin_amdgcn_mfma_f32_16x16x32_f16(
                        af[mi], bf[nj], acc[mi][nj], 0, 0, 0);
        }
    }
#undef LOADREGS

#pragma unroll
    for (int nj = 0; nj < 4; nj++) {
        int j = j0 + wc * 64 + nj * 16 + l15;
        float bb = bias[j];
#pragma unroll
        for (int mi = 0; mi < 4; mi++)
#pragma unroll
            for (int r = 0; r < 4; r++) {
                int n = n0 + wr * 64 + mi * 16 + 4 * g + r;
                outp[(size_t)n * J + j] = acc[mi][nj][r] + bb;
            }
    }
}

// ---------------------------------------------------------------------------
// MFMA flash attention (f16) — verified R4 structure, unchanged.
// ---------------------------------------------------------------------------
__device__ __forceinline__ u32x2 ds_tr16(const unsigned short* p) {
    u32x2 r;
    asm volatile("ds_read_b64_tr_b16 %0, %1"
                 : "=v"(r)
                 : "v"((unsigned int)(unsigned long long)p));
    return r;
}

__global__ __launch_bounds__(256, 4) void attn_mfma(
    const unsigned short* __restrict__ q,
    const unsigned short* __restrict__ k,
    const unsigned short* __restrict__ v,
    unsigned short* __restrict__ aout)
{
    __shared__ __align__(16) unsigned short Ks[64 * 64];   // swizzled [key][dim]
    __shared__ __align__(16) unsigned short Vs[4 * 1056];  // [db][key][16]

    const int h = blockIdx.y, b = blockIdx.z;
    const int tid = threadIdx.x;
    const int w = tid >> 6;
    const int lane = tid & 63;
    const int l15 = lane & 15, g = lane >> 4;
    const int bh = b * HH + h;
    const size_t base = (size_t)bh * TT * 64;
    const unsigned short* Qp = q + base;
    const unsigned short* Kp = k + base;
    const unsigned short* Vp = v + base;

    const float SC = 0.18033688011112042f;   // log2(e)/8

    u32x4 kreg[2];
    u32x2 vreg[4];
#define LOADKV(KB)                                                             \
    {                                                                          \
        _Pragma("unroll")                                                      \
        for (int it = 0; it < 2; it++) {                                       \
            int vi = tid + it * 256;                                           \
            int key = vi >> 3, pr = vi & 7;                                    \
            kreg[it] = *(const u32x4*)(Kp + (size_t)((KB) + key) * 64 + pr * 8);\
        }                                                                      \
        _Pragma("unroll")                                                      \
        for (int it = 0; it < 4; it++) {                                       \
            int vi = tid + it * 256;                                           \
            int key = vi >> 4, c4 = vi & 15;                                   \
            vreg[it] = *(const u32x2*)(Vp + (size_t)((KB) + key) * 64 + c4 * 4);\
        }                                                                      \
    }

    for (int ph = 0; ph < 2; ph++) {
        const int qt = ph ? (31 - (int)blockIdx.x) : (int)blockIdx.x;
        const int q0 = qt * 64;

        f16x8 qf[2];
        {
            const unsigned short* Qr = Qp + (size_t)(q0 + w * 16 + l15) * 64;
#pragma unroll
            for (int c = 0; c < 2; c++) {
                u32x2 a0 = *(const u32x2*)(Qr + 32 * c + 4 * g);
                u32x2 a1 = *(const u32x2*)(Qr + 32 * c + 16 + 4 * g);
                u32x4 uu = {a0.x, a0.y, a1.x, a1.y};
                qf[c] = __builtin_bit_cast(f16x8, uu);
            }
        }

        float mrow = -1e30f, lrow = 0.f;
        f32x4 accO[4];
#pragma unroll
        for (int nb = 0; nb < 4; nb++) accO[nb] = (f32x4){0.f, 0.f, 0.f, 0.f};

        const int ntiles = qt + 1;
        LOADKV(0)

        for (int kt = 0; kt < ntiles; kt++) {
            const bool diag = (kt == qt);
            __syncthreads();
#pragma unroll
            for (int it = 0; it < 2; it++) {
                int vi = tid + it * 256;
                int key = vi >> 3, pr = vi & 7;
                *(u32x4*)(Ks + key * 64 + ((pr ^ (key & 7)) << 3)) = kreg[it];
            }
#pragma unroll
            for (int it = 0; it < 4; it++) {
                int vi = tid + it * 256;
                int key = vi >> 4, c4 = vi & 15;
                *(u32x2*)(Vs + (c4 >> 2) * 1056 + key * 16 + (c4 & 3) * 4) = vreg[it];
            }
            __syncthreads();
            if (kt + 1 < ntiles) LOADKV((kt + 1) * 64)

            const int nkb = diag ? (w + 1) : 4;
            f32x4 accS[4];
#pragma unroll
            for (int kb = 0; kb < 4; kb++) accS[kb] = (f32x4){0.f, 0.f, 0.f, 0.f};
            __builtin_amdgcn_s_setprio(1);
#pragma unroll
            for (int kb = 0; kb < 4; kb++) {
                if (kb < nkb) {
                    int key = kb * 16 + l15;
                    int sw = key & 7;
#pragma unroll
                    for (int c = 0; c < 2; c++) {
                        int c8a = 8 * c + g, c8b = 8 * c + 4 + g;
                        u32x2 x0 = *(const u32x2*)(Ks + key * 64 +
                                       (((c8a >> 1) ^ sw) << 3) + ((c8a & 1) << 2));
                        u32x2 x1 = *(const u32x2*)(Ks + key * 64 +
                                       (((c8b >> 1) ^ sw) << 3) + ((c8b & 1) << 2));
                        u32x4 uu = {x0.x, x0.y, x1.x, x1.y};
                        accS[kb] = __builtin_amdgcn_mfma_f32_16x16x32_f16(
                            __builtin_bit_cast(f16x8, uu), qf[c], accS[kb], 0, 0, 0);
                    }
                }
            }
            __builtin_amdgcn_s_setprio(0);

            float sloc[16];
            float tmax = -1e30f;
            if (diag) {
#pragma unroll
                for (int kb = 0; kb < 4; kb++)
#pragma unroll
                    for (int r = 0; r < 4; r++) {
                        float s = accS[kb][r];
                        bool valid = (kb * 16 + 4 * g + r <= w * 16 + l15);
                        s = valid ? s : -1e30f;
                        sloc[kb * 4 + r] = s;
                        tmax = fmaxf(tmax, s);
                    }
            } else {
#pragma unroll
                for (int kb = 0; kb < 4; kb++)
#pragma unroll
                    for (int r = 0; r < 4; r++) {
                        float s = accS[kb][r];
                        sloc[kb * 4 + r] = s;
                        tmax = fmaxf(tmax, s);
                    }
            }
            tmax = fmaxf(tmax, __shfl_xor(tmax, 16));
            tmax = fmaxf(tmax, __shfl_xor(tmax, 32));

            if (!__all(tmax - mrow <= 61.0f)) {     // 61*SC = 11 log2-units
                float mnew = fmaxf(mrow, tmax);
                float sf = exp2f((mrow - mnew) * SC);
                mrow = mnew;
                lrow *= sf;
                float sfr[4];
#pragma unroll
                for (int r = 0; r < 4; r++) sfr[r] = __shfl(sf, 4 * g + r);
#pragma unroll
                for (int nb = 0; nb < 4; nb++)
#pragma unroll
                    for (int r = 0; r < 4; r++) accO[nb][r] *= sfr[r];
            }

            const float nmsc = -mrow * SC;
            unsigned int pw[8];
            float psum = 0.f;
#pragma unroll
            for (int i = 0; i < 8; i++) {
                float p0 = exp2f(fmaf(sloc[2 * i],     SC, nmsc));
                float p1 = exp2f(fmaf(sloc[2 * i + 1], SC, nmsc));
                pw[i] = pkrtz(p0, p1);
                psum += p0 + p1;
            }
            psum += __shfl_xor(psum, 16);
            psum += __shfl_xor(psum, 32);
            lrow += psum;

            const int nkc = (diag && w < 2) ? 1 : 2;
#pragma unroll
            for (int kc = 0; kc < 2; kc++)
                if (kc < nkc) {
                    u32x2 vfr[4][2];
#pragma unroll
                    for (int nb = 0; nb < 4; nb++)
#pragma unroll
                        for (int t2 = 0; t2 < 2; t2++)
                            vfr[nb][t2] = ds_tr16(
                                Vs + nb * 1056 + (kc * 32 + 16 * t2) * 16 + 4 * lane);
                    asm volatile("s_waitcnt lgkmcnt(0)" ::: "memory");
                    __builtin_amdgcn_sched_barrier(0);
                    u32x4 pu = {pw[4 * kc + 0], pw[4 * kc + 1], pw[4 * kc + 2], pw[4 * kc + 3]};
                    f16x8 pf = __builtin_bit_cast(f16x8, pu);
                    __builtin_amdgcn_s_setprio(1);
#pragma unroll
                    for (int nb = 0; nb < 4; nb++) {
                        u32x4 vu = {vfr[nb][0].x, vfr[nb][0].y,
                                    vfr[nb][1].x, vfr[nb][1].y};
                        accO[nb] = __builtin_amdgcn_mfma_f32_16x16x32_f16(
                            pf, __builtin_bit_cast(f16x8, vu), accO[nb], 0, 0, 0);
                    }
                    __builtin_amdgcn_s_setprio(0);
                }
        }

        float linv = 1.0f / lrow;
        float sfr[4];
#pragma unroll
        for (int r = 0; r < 4; r++) sfr[r] = __shfl(linv, 4 * g + r);
#pragma unroll
        for (int r = 0; r < 4; r++) {
            int qr = q0 + w * 16 + 4 * g + r;
            unsigned short* orow = aout + (size_t)(b * TT + qr) * DD + h * 64;
#pragma unroll
            for (int nb = 0; nb < 4; nb++)
                orow[nb * 16 + l15] = f2h(accO[nb][r] * sfr[r]);
        }
    }
#undef LOADKV
}

// ---------------------------------------------------------------------------
extern "C" void kernel_launch(void* const* d_in, const int* in_sizes, int n_in,
                              void* d_out, int out_size, void* d_ws, size_t ws_size,
                              hipStream_t stream)
{
    const float* x  = (const float*)d_in[0];
    const float* Wq = (const float*)d_in[1];
    const float* bq = (const float*)d_in[2];
    const float* Wk = (const float*)d_in[3];
    const float* bk = (const float*)d_in[4];
    const float* Wv = (const float*)d_in[5];
    const float* bv = (const float*)d_in[6];
    const float* Wo = (const float*)d_in[7];
    const float* bo = (const float*)d_in[8];
    float* out = (float*)d_out;                     // FLOAT32 output [B,T,D]

    const size_t NE = (size_t)BB * HH * TT * HD;    // 8388608 elements
    // ws (50.3 MB): q|k|v f16 contiguous.
    unsigned short* qkv  = (unsigned short*)d_ws;
    unsigned short* qb   = qkv;
    unsigned short* kbuf = qkv + NE;
    unsigned short* vbuf = qkv + 2 * NE;
    float* res = (float*)d_ws;                      // overlays dead q+k after attn

    // d_out scratch layout (all dead before final result lands):
    //  [0 .. 16.78M)   x_h f16  (later overwritten by att_h f16)
    //  [16.78M ..)     wq|wk|wv|wo f16 contiguous (2 MB each)
    unsigned short* ds  = (unsigned short*)d_out;
    unsigned short* xh  = ds;
    unsigned short* wh  = ds + 8388608;             // wq at 0, wk +1M, wv +2M, wo +3M
    unsigned short* woh = wh + 3145728;
    unsigned short* att = ds;                       // att_h overlays dead x_h

    const int N = BB * TT;                          // 8192 tokens
    dim3 blk(256);

    // 1) convert x + all W to f16 (single launch)
    conv_all<<<12288, blk, 0, stream>>>(
        (const float4*)x, (const float4*)Wq, (const float4*)Wk,
        (const float4*)Wv, (const float4*)Wo, (ushort4*)xh, (ushort4*)wh);

    // 2) fused QKV projection + RoPE (single launch, XCD-swizzled)
    gemm_qkv<<<1536, blk, 0, stream>>>(xh, wh, bq, bk, bv, qkv);

    // 3) flash attention -> f16 att scratch in d_out (x_h dead)
    attn_mfma<<<dim3(TT / 128, HH, BB), blk, 0, stream>>>(qb, kbuf, vbuf, att);

    // 4) O-projection -> f32 res (dead q+k ws region)
    gemm_h<<<dim3(DD / 128, N / 128), blk, 0, stream>>>(att, woh, bo, res, N, DD, DD);

    // 5) final result -> d_out
    hipMemcpyAsync(out, res, (size_t)N * DD * sizeof(float),
                   hipMemcpyDeviceToDevice, stream);
}

// Round 6
// 325.358 us; speedup vs baseline: 1.6550x; 1.6550x over previous
//
#include <hip/hip_runtime.h>

// Problem constants: B=4, T=2048, D=1024, H=16, HD=64
// Math (certified r6): torch convention x@W.T+b, rotate-half RoPE pos=t+1,
// causal softmax(QK^T/8)V, O-proj. Output f32 [B,T,D].
// R6: fix R5's scratch-spill regression (WRITE_SIZE 33x over-write, VGPR=104
// < live set): RoPE trig moved OUT of the gemm epilogue into a precomputed
// (cos,sin) f32 table (2048x32, built in conv_all). gemm_qkv main loop is
// the verbatim-verified R2 body. Fused-launch structure of R5 kept.
#define BB 4
#define TT 2048
#define DD 1024
#define HH 16
#define HD 64

typedef __attribute__((ext_vector_type(8))) _Float16 f16x8;
typedef __attribute__((ext_vector_type(4))) float f32x4;
typedef __attribute__((ext_vector_type(2))) unsigned int u32x2;
typedef __attribute__((ext_vector_type(4))) unsigned int u32x4;

__device__ __forceinline__ float h2f(unsigned short u) {
    return (float)__builtin_bit_cast(_Float16, u);
}
__device__ __forceinline__ unsigned short f2h(float f) {
    return __builtin_bit_cast(unsigned short, (_Float16)f);
}
__device__ __forceinline__ unsigned int pkrtz(float a, float b) {
    return __builtin_bit_cast(unsigned int, __builtin_amdgcn_cvt_pkrtz(a, b));
}

// ---------------------------------------------------------------------------
// Fused f32 -> f16 convert for x + Wq|Wk|Wv|Wo  PLUS RoPE (cos,sin) table.
// Grid 12544: [0,8192) x, [8192,12288) W's, [12288,12544) rope table.
// ---------------------------------------------------------------------------
__global__ __launch_bounds__(256) void conv_all(
    const float4* __restrict__ x,
    const float4* __restrict__ Wq, const float4* __restrict__ Wk,
    const float4* __restrict__ Wv, const float4* __restrict__ Wo,
    ushort4* __restrict__ xh, ushort4* __restrict__ wh,
    float2* __restrict__ tab)
{
    int vi = blockIdx.x * 256 + threadIdx.x;
    if (vi < 2097152) {
        float4 v = x[vi];
        xh[vi] = (ushort4){ f2h(v.x), f2h(v.y), f2h(v.z), f2h(v.w) };
    } else if (vi < 3145728) {
        int u = vi - 2097152;               // [0, 1048576)
        int w = u >> 18;                    // 0..3 (uniform per block)
        const float4* src = (w == 0) ? Wq : (w == 1) ? Wk : (w == 2) ? Wv : Wo;
        float4 v = src[u & 262143];
        wh[u] = (ushort4){ f2h(v.x), f2h(v.y), f2h(v.z), f2h(v.w) };
    } else {
        int u = vi - 3145728;               // [0, 65536): (t, i)
        int t = u >> 5, i = u & 31;
        float ang = (float)(t + 1) *
                    exp2f(-(float)i * (13.287712379549449f / 32.0f));
        tab[u] = (float2){ cosf(ang), sinf(ang) };
    }
}

// ---------------------------------------------------------------------------
// Fused QKV MFMA GEMM + table-based RoPE epilogue.
// Grid 1536 (1D, XCD-swizzled): sel(q/k/v) x 8 j-blocks x 64 n-blocks.
// Main loop = verbatim verified R2 gemm_h body (no trig, no calls).
// ---------------------------------------------------------------------------
__global__ __launch_bounds__(256) void gemm_qkv(
    const unsigned short* __restrict__ A,      // x_h [8192][1024]
    const unsigned short* __restrict__ Wall,   // wq|wk|wv f16 [3][1024][1024]
    const float* __restrict__ bq, const float* __restrict__ bk,
    const float* __restrict__ bv,
    const float2* __restrict__ tab,            // [2048][32] (cos,sin)
    unsigned short* __restrict__ qkv)          // q|k|v f16 [3][B,H,T,64]
{
    __shared__ __align__(16) unsigned short As[128 * 64];
    __shared__ __align__(16) unsigned short Ws[128 * 64];

    // bijective XCD swizzle: 1536 blocks -> 192 contiguous per XCD
    int bid = blockIdx.x;
    int swz = (bid & 7) * 192 + (bid >> 3);
    int bx = swz % 24, by = swz / 24;
    const int sel = bx >> 3;                   // 0=q 1=k 2=v
    const int jb = bx & 7;
    const int n0 = by * 128;
    const int j0 = jb * 128;

    const unsigned short* W = Wall + (size_t)sel * 1048576;
    const float* bias = (sel == 0) ? bq : (sel == 1) ? bk : bv;
    unsigned short* outp = qkv + (size_t)sel * (BB * HH * TT * HD);

    const int tid = threadIdx.x;
    const int w = tid >> 6, lane = tid & 63;
    const int l15 = lane & 15, g = lane >> 4;
    const int wr = w >> 1, wc = w & 1;

    f32x4 acc[4][4];
#pragma unroll
    for (int mi = 0; mi < 4; mi++)
#pragma unroll
        for (int nj = 0; nj < 4; nj++) acc[mi][nj] = (f32x4){0.f, 0.f, 0.f, 0.f};

    u32x4 pa[4], pb[4];
#define LOADREGS(KS)                                                             \
    {                                                                            \
        _Pragma("unroll")                                                        \
        for (int it = 0; it < 4; it++) {                                         \
            int ci = tid + it * 256;                                             \
            int r = ci >> 3, p = ci & 7;                                         \
            pa[it] = *(const u32x4*)(A + (size_t)(n0 + r) * 1024 + (KS) + p * 8);\
            pb[it] = *(const u32x4*)(W + (size_t)(j0 + r) * 1024 + (KS) + p * 8);\
        }                                                                        \
    }

    LOADREGS(0)

    for (int ks = 0; ks < 1024; ks += 64) {
        __syncthreads();
#pragma unroll
        for (int it = 0; it < 4; it++) {
            int ci = tid + it * 256;
            int r = ci >> 3, p = ci & 7;
            int d = r * 64 + ((p ^ (r & 7)) << 3);
            *(u32x4*)(As + d) = pa[it];
            *(u32x4*)(Ws + d) = pb[it];
        }
        __syncthreads();
        if (ks + 64 < 1024) LOADREGS(ks + 64)

#pragma unroll
        for (int c = 0; c < 2; c++) {
            f16x8 af[4], bf[4];
            const int q0c = c * 4 + (g >> 1);
            const int q1c = q0c + 2;
            const int off = (g & 1) << 2;
#pragma unroll
            for (int mi = 0; mi < 4; mi++) {
                int r = wr * 64 + mi * 16 + l15;
                int sw = r & 7;
                const unsigned short* rp = As + r * 64;
                u32x2 x0 = *(const u32x2*)(rp + ((q0c ^ sw) << 3) + off);
                u32x2 x1 = *(const u32x2*)(rp + ((q1c ^ sw) << 3) + off);
                u32x4 uu = {x0.x, x0.y, x1.x, x1.y};
                af[mi] = __builtin_bit_cast(f16x8, uu);
            }
#pragma unroll
            for (int nj = 0; nj < 4; nj++) {
                int r = wc * 64 + nj * 16 + l15;
                int sw = r & 7;
                const unsigned short* rp = Ws + r * 64;
                u32x2 x0 = *(const u32x2*)(rp + ((q0c ^ sw) << 3) + off);
                u32x2 x1 = *(const u32x2*)(rp + ((q1c ^ sw) << 3) + off);
                u32x4 uu = {x0.x, x0.y, x1.x, x1.y};
                bf[nj] = __builtin_bit_cast(f16x8, uu);
            }
#pragma unroll
            for (int mi = 0; mi < 4; mi++)
#pragma unroll
                for (int nj = 0; nj < 4; nj++)
                    acc[mi][nj] = __builtin_amdgcn_mfma_f32_16x16x32_f16(
                        af[mi], bf[nj], acc[mi][nj], 0, 0, 0);
        }
    }
#undef LOADREGS

    // ---- epilogue (no trig: table-based RoPE) ----
    float bb4[4];
#pragma unroll
    for (int nj = 0; nj < 4; nj++) bb4[nj] = bias[j0 + wc * 64 + nj * 16 + l15];
    const int hh = (j0 >> 6) + wc;             // head 0..15

    if (sel == 2) {
        // V: plain scatter
#pragma unroll
        for (int mi = 0; mi < 4; mi++)
#pragma unroll
            for (int r = 0; r < 4; r++) {
                int n = n0 + wr * 64 + mi * 16 + 4 * g + r;
                int b = n >> 11, t = n & (TT - 1);
                size_t rowbase = ((size_t)(b * HH + hh) * TT + t) << 6;
#pragma unroll
                for (int nj = 0; nj < 4; nj++) {
                    int dd = nj * 16 + l15;
                    outp[rowbase + dd] = f2h(acc[mi][nj][r] + bb4[nj]);
                }
            }
    } else {
        // Q/K: rotate-half RoPE, (c,s) from table. Pair (p, p+2) = (i, i+32),
        // i = p*16 + l15; all 16 lanes of a group share t -> coalesced loads.
#pragma unroll
        for (int mi = 0; mi < 4; mi++)
#pragma unroll
            for (int r = 0; r < 4; r++) {
                int n = n0 + wr * 64 + mi * 16 + 4 * g + r;
                int b = n >> 11, t = n & (TT - 1);
                size_t rowbase = ((size_t)(b * HH + hh) * TT + t) << 6;
                const float2* tp = tab + t * 32 + l15;
#pragma unroll
                for (int p = 0; p < 2; p++) {
                    float2 cs = tp[p * 16];
                    float x1 = acc[mi][p][r]     + bb4[p];
                    float x2 = acc[mi][p + 2][r] + bb4[p + 2];
                    int i = p * 16 + l15;
                    outp[rowbase + i]      = f2h(x1 * cs.x - x2 * cs.y);
                    outp[rowbase + i + 32] = f2h(x2 * cs.x + x1 * cs.y);
                }
            }
    }
}

// ---------------------------------------------------------------------------
// MFMA f16 GEMM for O-projection (verified R2 structure + XCD swizzle).
// ---------------------------------------------------------------------------
__global__ __launch_bounds__(256) void gemm_h(
    const unsigned short* __restrict__ A, const unsigned short* __restrict__ W,
    const float* __restrict__ bias, float* __restrict__ outp,
    int N, int K, int J)
{
    __shared__ __align__(16) unsigned short As[128 * 64];
    __shared__ __align__(16) unsigned short Ws[128 * 64];

    int total = gridDim.x * gridDim.y;
    int flat = blockIdx.y * gridDim.x + blockIdx.x;
    int swz = (flat & 7) * (total >> 3) + (flat >> 3);
    int bxi = swz % gridDim.x, byi = swz / gridDim.x;

    const int tid = threadIdx.x;
    const int w = tid >> 6, lane = tid & 63;
    const int l15 = lane & 15, g = lane >> 4;
    const int wr = w >> 1, wc = w & 1;
    const int n0 = byi * 128;
    const int j0 = bxi * 128;

    f32x4 acc[4][4];
#pragma unroll
    for (int mi = 0; mi < 4; mi++)
#pragma unroll
        for (int nj = 0; nj < 4; nj++) acc[mi][nj] = (f32x4){0.f, 0.f, 0.f, 0.f};

    u32x4 pa[4], pb[4];
#define LOADREGS(KS)                                                          \
    {                                                                         \
        _Pragma("unroll")                                                     \
        for (int it = 0; it < 4; it++) {                                      \
            int ci = tid + it * 256;                                          \
            int r = ci >> 3, p = ci & 7;                                      \
            pa[it] = *(const u32x4*)(A + (size_t)(n0 + r) * K + (KS) + p * 8);\
            pb[it] = *(const u32x4*)(W + (size_t)(j0 + r) * K + (KS) + p * 8);\
        }                                                                     \
    }

    LOADREGS(0)

    for (int ks = 0; ks < K; ks += 64) {
        __syncthreads();
#pragma unroll
        for (int it = 0; it < 4; it++) {
            int ci = tid + it * 256;
            int r = ci >> 3, p = ci & 7;
            int d = r * 64 + ((p ^ (r & 7)) << 3);
            *(u32x4*)(As + d) = pa[it];
            *(u32x4*)(Ws + d) = pb[it];
        }
        __syncthreads();
        if (ks + 64 < K) LOADREGS(ks + 64)

#pragma unroll
        for (int c = 0; c < 2; c++) {
            f16x8 af[4], bf[4];
            const int q0c = c * 4 + (g >> 1);
            const int q1c = q0c + 2;
            const int off = (g & 1) << 2;
#pragma unroll
            for (int mi = 0; mi < 4; mi++) {
                int r = wr * 64 + mi * 16 + l15;
                int sw = r & 7;
                const unsigned short* rp = As + r * 64;
                u32x2 x0 = *(const u32x2*)(rp + ((q0c ^ sw) << 3) + off);
                u32x2 x1 = *(const u32x2*)(rp + ((q1c ^ sw) << 3) + off);
                u32x4 uu = {x0.x, x0.y, x1.x, x1.y};
                af[mi] = __builtin_bit_cast(f16x8, uu);
            }
#pragma unroll
            for (int nj = 0; nj < 4; nj++) {
                int r = wc * 64 + nj * 16 + l15;
                int sw = r & 7;
                const unsigned short* rp = Ws + r * 64;
                u32x2 x0 = *(const u32x2*)(rp + ((q0c ^ sw) << 3) + off);
                u32x2 x1 = *(const u32x2*)(rp + ((q1c ^ sw) << 3) + off);
                u32x4 uu = {x0.x, x0.y, x1.x, x1.y};
                bf[nj] = __builtin_bit_cast(f16x8, uu);
            }
#pragma unroll
            for (int mi = 0; mi < 4; mi++)
#pragma unroll
                for (int nj = 0; nj < 4; nj++)
                    acc[mi][nj] = __builtin_amdgcn_mfma_f32_16x16x32_f16(
                        af[mi], bf[nj], acc[mi][nj], 0, 0, 0);
        }
    }
#undef LOADREGS

#pragma unroll
    for (int nj = 0; nj < 4; nj++) {
        int j = j0 + wc * 64 + nj * 16 + l15;
        float bb = bias[j];
#pragma unroll
        for (int mi = 0; mi < 4; mi++)
#pragma unroll
            for (int r = 0; r < 4; r++) {
                int n = n0 + wr * 64 + mi * 16 + 4 * g + r;
                outp[(size_t)n * J + j] = acc[mi][nj][r] + bb;
            }
    }
}

// ---------------------------------------------------------------------------
// MFMA flash attention (f16) — verified R4 structure, unchanged.
// ---------------------------------------------------------------------------
__device__ __forceinline__ u32x2 ds_tr16(const unsigned short* p) {
    u32x2 r;
    asm volatile("ds_read_b64_tr_b16 %0, %1"
                 : "=v"(r)
                 : "v"((unsigned int)(unsigned long long)p));
    return r;
}

__global__ __launch_bounds__(256, 4) void attn_mfma(
    const unsigned short* __restrict__ q,
    const unsigned short* __restrict__ k,
    const unsigned short* __restrict__ v,
    unsigned short* __restrict__ aout)
{
    __shared__ __align__(16) unsigned short Ks[64 * 64];   // swizzled [key][dim]
    __shared__ __align__(16) unsigned short Vs[4 * 1056];  // [db][key][16]

    const int h = blockIdx.y, b = blockIdx.z;
    const int tid = threadIdx.x;
    const int w = tid >> 6;
    const int lane = tid & 63;
    const int l15 = lane & 15, g = lane >> 4;
    const int bh = b * HH + h;
    const size_t base = (size_t)bh * TT * 64;
    const unsigned short* Qp = q + base;
    const unsigned short* Kp = k + base;
    const unsigned short* Vp = v + base;

    const float SC = 0.18033688011112042f;   // log2(e)/8

    u32x4 kreg[2];
    u32x2 vreg[4];
#define LOADKV(KB)                                                             \
    {                                                                          \
        _Pragma("unroll")                                                      \
        for (int it = 0; it < 2; it++) {                                       \
            int vi = tid + it * 256;                                           \
            int key = vi >> 3, pr = vi & 7;                                    \
            kreg[it] = *(const u32x4*)(Kp + (size_t)((KB) + key) * 64 + pr * 8);\
        }                                                                      \
        _Pragma("unroll")                                                      \
        for (int it = 0; it < 4; it++) {                                       \
            int vi = tid + it * 256;                                           \
            int key = vi >> 4, c4 = vi & 15;                                   \
            vreg[it] = *(const u32x2*)(Vp + (size_t)((KB) + key) * 64 + c4 * 4);\
        }                                                                      \
    }

    for (int ph = 0; ph < 2; ph++) {
        const int qt = ph ? (31 - (int)blockIdx.x) : (int)blockIdx.x;
        const int q0 = qt * 64;

        f16x8 qf[2];
        {
            const unsigned short* Qr = Qp + (size_t)(q0 + w * 16 + l15) * 64;
#pragma unroll
            for (int c = 0; c < 2; c++) {
                u32x2 a0 = *(const u32x2*)(Qr + 32 * c + 4 * g);
                u32x2 a1 = *(const u32x2*)(Qr + 32 * c + 16 + 4 * g);
                u32x4 uu = {a0.x, a0.y, a1.x, a1.y};
                qf[c] = __builtin_bit_cast(f16x8, uu);
            }
        }

        float mrow = -1e30f, lrow = 0.f;
        f32x4 accO[4];
#pragma unroll
        for (int nb = 0; nb < 4; nb++) accO[nb] = (f32x4){0.f, 0.f, 0.f, 0.f};

        const int ntiles = qt + 1;
        LOADKV(0)

        for (int kt = 0; kt < ntiles; kt++) {
            const bool diag = (kt == qt);
            __syncthreads();
#pragma unroll
            for (int it = 0; it < 2; it++) {
                int vi = tid + it * 256;
                int key = vi >> 3, pr = vi & 7;
                *(u32x4*)(Ks + key * 64 + ((pr ^ (key & 7)) << 3)) = kreg[it];
            }
#pragma unroll
            for (int it = 0; it < 4; it++) {
                int vi = tid + it * 256;
                int key = vi >> 4, c4 = vi & 15;
                *(u32x2*)(Vs + (c4 >> 2) * 1056 + key * 16 + (c4 & 3) * 4) = vreg[it];
            }
            __syncthreads();
            if (kt + 1 < ntiles) LOADKV((kt + 1) * 64)

            const int nkb = diag ? (w + 1) : 4;
            f32x4 accS[4];
#pragma unroll
            for (int kb = 0; kb < 4; kb++) accS[kb] = (f32x4){0.f, 0.f, 0.f, 0.f};
            __builtin_amdgcn_s_setprio(1);
#pragma unroll
            for (int kb = 0; kb < 4; kb++) {
                if (kb < nkb) {
                    int key = kb * 16 + l15;
                    int sw = key & 7;
#pragma unroll
                    for (int c = 0; c < 2; c++) {
                        int c8a = 8 * c + g, c8b = 8 * c + 4 + g;
                        u32x2 x0 = *(const u32x2*)(Ks + key * 64 +
                                       (((c8a >> 1) ^ sw) << 3) + ((c8a & 1) << 2));
                        u32x2 x1 = *(const u32x2*)(Ks + key * 64 +
                                       (((c8b >> 1) ^ sw) << 3) + ((c8b & 1) << 2));
                        u32x4 uu = {x0.x, x0.y, x1.x, x1.y};
                        accS[kb] = __builtin_amdgcn_mfma_f32_16x16x32_f16(
                            __builtin_bit_cast(f16x8, uu), qf[c], accS[kb], 0, 0, 0);
                    }
                }
            }
            __builtin_amdgcn_s_setprio(0);

            float sloc[16];
            float tmax = -1e30f;
            if (diag) {
#pragma unroll
                for (int kb = 0; kb < 4; kb++)
#pragma unroll
                    for (int r = 0; r < 4; r++) {
                        float s = accS[kb][r];
                        bool valid = (kb * 16 + 4 * g + r <= w * 16 + l15);
                        s = valid ? s : -1e30f;
                        sloc[kb * 4 + r] = s;
                        tmax = fmaxf(tmax, s);
                    }
            } else {
#pragma unroll
                for (int kb = 0; kb < 4; kb++)
#pragma unroll
                    for (int r = 0; r < 4; r++) {
                        float s = accS[kb][r];
                        sloc[kb * 4 + r] = s;
                        tmax = fmaxf(tmax, s);
                    }
            }
            tmax = fmaxf(tmax, __shfl_xor(tmax, 16));
            tmax = fmaxf(tmax, __shfl_xor(tmax, 32));

            if (!__all(tmax - mrow <= 61.0f)) {     // 61*SC = 11 log2-units
                float mnew = fmaxf(mrow, tmax);
                float sf = exp2f((mrow - mnew) * SC);
                mrow = mnew;
                lrow *= sf;
                float sfr[4];
#pragma unroll
                for (int r = 0; r < 4; r++) sfr[r] = __shfl(sf, 4 * g + r);
#pragma unroll
                for (int nb = 0; nb < 4; nb++)
#pragma unroll
                    for (int r = 0; r < 4; r++) accO[nb][r] *= sfr[r];
            }

            const float nmsc = -mrow * SC;
            unsigned int pw[8];
            float psum = 0.f;
#pragma unroll
            for (int i = 0; i < 8; i++) {
                float p0 = exp2f(fmaf(sloc[2 * i],     SC, nmsc));
                float p1 = exp2f(fmaf(sloc[2 * i + 1], SC, nmsc));
                pw[i] = pkrtz(p0, p1);
                psum += p0 + p1;
            }
            psum += __shfl_xor(psum, 16);
            psum += __shfl_xor(psum, 32);
            lrow += psum;

            const int nkc = (diag && w < 2) ? 1 : 2;
#pragma unroll
            for (int kc = 0; kc < 2; kc++)
                if (kc < nkc) {
                    u32x2 vfr[4][2];
#pragma unroll
                    for (int nb = 0; nb < 4; nb++)
#pragma unroll
                        for (int t2 = 0; t2 < 2; t2++)
                            vfr[nb][t2] = ds_tr16(
                                Vs + nb * 1056 + (kc * 32 + 16 * t2) * 16 + 4 * lane);
                    asm volatile("s_waitcnt lgkmcnt(0)" ::: "memory");
                    __builtin_amdgcn_sched_barrier(0);
                    u32x4 pu = {pw[4 * kc + 0], pw[4 * kc + 1], pw[4 * kc + 2], pw[4 * kc + 3]};
                    f16x8 pf = __builtin_bit_cast(f16x8, pu);
                    __builtin_amdgcn_s_setprio(1);
#pragma unroll
                    for (int nb = 0; nb < 4; nb++) {
                        u32x4 vu = {vfr[nb][0].x, vfr[nb][0].y,
                                    vfr[nb][1].x, vfr[nb][1].y};
                        accO[nb] = __builtin_amdgcn_mfma_f32_16x16x32_f16(
                            pf, __builtin_bit_cast(f16x8, vu), accO[nb], 0, 0, 0);
                    }
                    __builtin_amdgcn_s_setprio(0);
                }
        }

        float linv = 1.0f / lrow;
        float sfr[4];
#pragma unroll
        for (int r = 0; r < 4; r++) sfr[r] = __shfl(linv, 4 * g + r);
#pragma unroll
        for (int r = 0; r < 4; r++) {
            int qr = q0 + w * 16 + 4 * g + r;
            unsigned short* orow = aout + (size_t)(b * TT + qr) * DD + h * 64;
#pragma unroll
            for (int nb = 0; nb < 4; nb++)
                orow[nb * 16 + l15] = f2h(accO[nb][r] * sfr[r]);
        }
    }
#undef LOADKV
}

// ---------------------------------------------------------------------------
extern "C" void kernel_launch(void* const* d_in, const int* in_sizes, int n_in,
                              void* d_out, int out_size, void* d_ws, size_t ws_size,
                              hipStream_t stream)
{
    const float* x  = (const float*)d_in[0];
    const float* Wq = (const float*)d_in[1];
    const float* bq = (const float*)d_in[2];
    const float* Wk = (const float*)d_in[3];
    const float* bk = (const float*)d_in[4];
    const float* Wv = (const float*)d_in[5];
    const float* bv = (const float*)d_in[6];
    const float* Wo = (const float*)d_in[7];
    const float* bo = (const float*)d_in[8];
    float* out = (float*)d_out;                     // FLOAT32 output [B,T,D]

    const size_t NE = (size_t)BB * HH * TT * HD;    // 8388608 elements
    // ws (50.3 MB): q|k|v f16 contiguous.
    unsigned short* qkv  = (unsigned short*)d_ws;
    unsigned short* qb   = qkv;
    unsigned short* kbuf = qkv + NE;
    unsigned short* vbuf = qkv + 2 * NE;
    float* res = (float*)d_ws;                      // overlays dead q+k after attn

    // d_out scratch layout (all dead before final result lands):
    //  [0 .. 16.78M)      x_h f16  (later overwritten by att_h f16)
    //  [16.78M .. 25.17M) wq|wk|wv|wo f16 contiguous (2 MB each)
    //  [25.17M .. 25.69M) rope table float2 [2048][32]
    unsigned short* ds  = (unsigned short*)d_out;
    unsigned short* xh  = ds;
    unsigned short* wh  = ds + 8388608;             // wq, wk +1M, wv +2M, wo +3M
    unsigned short* woh = wh + 3145728;
    float2* tab = (float2*)(ds + 12582912);
    unsigned short* att = ds;                       // att_h overlays dead x_h

    const int N = BB * TT;                          // 8192 tokens
    dim3 blk(256);

    // 1) convert x + all W to f16, build rope table (single launch)
    conv_all<<<12544, blk, 0, stream>>>(
        (const float4*)x, (const float4*)Wq, (const float4*)Wk,
        (const float4*)Wv, (const float4*)Wo, (ushort4*)xh, (ushort4*)wh, tab);

    // 2) fused QKV projection + table RoPE (single launch, XCD-swizzled)
    gemm_qkv<<<1536, blk, 0, stream>>>(xh, wh, bq, bk, bv, tab, qkv);

    // 3) flash attention -> f16 att scratch in d_out (x_h dead)
    attn_mfma<<<dim3(TT / 128, HH, BB), blk, 0, stream>>>(qb, kbuf, vbuf, att);

    // 4) O-projection -> f32 res (dead q+k ws region)
    gemm_h<<<dim3(DD / 128, N / 128), blk, 0, stream>>>(att, woh, bo, res, N, DD, DD);

    // 5) final result -> d_out
    hipMemcpyAsync(out, res, (size_t)N * DD * sizeof(float),
                   hipMemcpyDeviceToDevice, stream);
}

// Round 9
// 313.072 us; speedup vs baseline: 1.7199x; 1.0392x over previous
//
#include <hip/hip_runtime.h>

// Problem constants: B=4, T=2048, D=1024, H=16, HD=64
// Math (certified r6): torch convention x@W.T+b, rotate-half RoPE pos=t+1,
// causal softmax(QK^T/8)V, O-proj. Output f32 [B,T,D].
// R9: isolation round. attn reverted to the VERIFIED R4/R6 single-strip
// kernel (two-strip R7/R8 failed deterministically; bug not yet found).
// Keeps R8 plumbing: conv_all (x + Wq|Wk|Wv + rope table), conv_wo after
// attn, direct-mode memcpy elimination (fallback = verified R6 layout).
#define BB 4
#define TT 2048
#define DD 1024
#define HH 16
#define HD 64

typedef __attribute__((ext_vector_type(8))) _Float16 f16x8;
typedef __attribute__((ext_vector_type(4))) float f32x4;
typedef __attribute__((ext_vector_type(2))) unsigned int u32x2;
typedef __attribute__((ext_vector_type(4))) unsigned int u32x4;

__device__ __forceinline__ float h2f(unsigned short u) {
    return (float)__builtin_bit_cast(_Float16, u);
}
__device__ __forceinline__ unsigned short f2h(float f) {
    return __builtin_bit_cast(unsigned short, (_Float16)f);
}
__device__ __forceinline__ unsigned int pkrtz(float a, float b) {
    return __builtin_bit_cast(unsigned int, __builtin_amdgcn_cvt_pkrtz(a, b));
}

// ---------------------------------------------------------------------------
// Fused f32 -> f16 convert: x + Wq|Wk|Wv + RoPE (cos,sin) table.
// Grid 11520: [0,8192) x, [8192,11264) W's, [11264,11520) table.
// ---------------------------------------------------------------------------
__global__ __launch_bounds__(256) void conv_all(
    const float4* __restrict__ x,
    const float4* __restrict__ Wq, const float4* __restrict__ Wk,
    const float4* __restrict__ Wv,
    ushort4* __restrict__ xh, ushort4* __restrict__ wh,
    float2* __restrict__ tab)
{
    int vi = blockIdx.x * 256 + threadIdx.x;
    if (vi < 2097152) {
        float4 v = x[vi];
        xh[vi] = (ushort4){ f2h(v.x), f2h(v.y), f2h(v.z), f2h(v.w) };
    } else if (vi < 2883584) {
        int u = vi - 2097152;               // [0, 786432)
        int w = u >> 18;                    // 0..2 (uniform per block)
        const float4* src = (w == 0) ? Wq : (w == 1) ? Wk : Wv;
        float4 v = src[u & 262143];
        wh[u] = (ushort4){ f2h(v.x), f2h(v.y), f2h(v.z), f2h(v.w) };
    } else {
        int u = vi - 2883584;               // [0, 65536): (t, i)
        int t = u >> 5, i = u & 31;
        float ang = (float)(t + 1) *
                    exp2f(-(float)i * (13.287712379549449f / 32.0f));
        tab[u] = (float2){ cosf(ang), sinf(ang) };
    }
}

// Wo f32 -> f16 (launched AFTER attn; dst never aliased with gemm_h writes).
__global__ __launch_bounds__(256) void conv_wo(
    const float4* __restrict__ Wo, ushort4* __restrict__ dst)
{
    int i = blockIdx.x * 256 + threadIdx.x;   // 262144 total
    float4 v = Wo[i];
    dst[i] = (ushort4){ f2h(v.x), f2h(v.y), f2h(v.z), f2h(v.w) };
}

// ---------------------------------------------------------------------------
// Fused QKV MFMA GEMM + table-based RoPE epilogue (verified R6, unchanged).
// ---------------------------------------------------------------------------
__global__ __launch_bounds__(256) void gemm_qkv(
    const unsigned short* __restrict__ A,      // x_h [8192][1024]
    const unsigned short* __restrict__ Wall,   // wq|wk|wv f16 [3][1024][1024]
    const float* __restrict__ bq, const float* __restrict__ bk,
    const float* __restrict__ bv,
    const float2* __restrict__ tab,            // [2048][32] (cos,sin)
    unsigned short* __restrict__ qkv)          // q|k|v f16 [3][B,H,T,64]
{
    __shared__ __align__(16) unsigned short As[128 * 64];
    __shared__ __align__(16) unsigned short Ws[128 * 64];

    int bid = blockIdx.x;
    int swz = (bid & 7) * 192 + (bid >> 3);
    int bx = swz % 24, by = swz / 24;
    const int sel = bx >> 3;                   // 0=q 1=k 2=v
    const int jb = bx & 7;
    const int n0 = by * 128;
    const int j0 = jb * 128;

    const unsigned short* W = Wall + (size_t)sel * 1048576;
    const float* bias = (sel == 0) ? bq : (sel == 1) ? bk : bv;
    unsigned short* outp = qkv + (size_t)sel * (BB * HH * TT * HD);

    const int tid = threadIdx.x;
    const int w = tid >> 6, lane = tid & 63;
    const int l15 = lane & 15, g = lane >> 4;
    const int wr = w >> 1, wc = w & 1;

    f32x4 acc[4][4];
#pragma unroll
    for (int mi = 0; mi < 4; mi++)
#pragma unroll
        for (int nj = 0; nj < 4; nj++) acc[mi][nj] = (f32x4){0.f, 0.f, 0.f, 0.f};

    u32x4 pa[4], pb[4];
#define LOADREGS(KS)                                                             \
    {                                                                            \
        _Pragma("unroll")                                                        \
        for (int it = 0; it < 4; it++) {                                         \
            int ci = tid + it * 256;                                             \
            int r = ci >> 3, p = ci & 7;                                         \
            pa[it] = *(const u32x4*)(A + (size_t)(n0 + r) * 1024 + (KS) + p * 8);\
            pb[it] = *(const u32x4*)(W + (size_t)(j0 + r) * 1024 + (KS) + p * 8);\
        }                                                                        \
    }

    LOADREGS(0)

    for (int ks = 0; ks < 1024; ks += 64) {
        __syncthreads();
#pragma unroll
        for (int it = 0; it < 4; it++) {
            int ci = tid + it * 256;
            int r = ci >> 3, p = ci & 7;
            int d = r * 64 + ((p ^ (r & 7)) << 3);
            *(u32x4*)(As + d) = pa[it];
            *(u32x4*)(Ws + d) = pb[it];
        }
        __syncthreads();
        if (ks + 64 < 1024) LOADREGS(ks + 64)

#pragma unroll
        for (int c = 0; c < 2; c++) {
            f16x8 af[4], bf[4];
            const int q0c = c * 4 + (g >> 1);
            const int q1c = q0c + 2;
            const int off = (g & 1) << 2;
#pragma unroll
            for (int mi = 0; mi < 4; mi++) {
                int r = wr * 64 + mi * 16 + l15;
                int sw = r & 7;
                const unsigned short* rp = As + r * 64;
                u32x2 x0 = *(const u32x2*)(rp + ((q0c ^ sw) << 3) + off);
                u32x2 x1 = *(const u32x2*)(rp + ((q1c ^ sw) << 3) + off);
                u32x4 uu = {x0.x, x0.y, x1.x, x1.y};
                af[mi] = __builtin_bit_cast(f16x8, uu);
            }
#pragma unroll
            for (int nj = 0; nj < 4; nj++) {
                int r = wc * 64 + nj * 16 + l15;
                int sw = r & 7;
                const unsigned short* rp = Ws + r * 64;
                u32x2 x0 = *(const u32x2*)(rp + ((q0c ^ sw) << 3) + off);
                u32x2 x1 = *(const u32x2*)(rp + ((q1c ^ sw) << 3) + off);
                u32x4 uu = {x0.x, x0.y, x1.x, x1.y};
                bf[nj] = __builtin_bit_cast(f16x8, uu);
            }
#pragma unroll
            for (int mi = 0; mi < 4; mi++)
#pragma unroll
                for (int nj = 0; nj < 4; nj++)
                    acc[mi][nj] = __builtin_amdgcn_mfma_f32_16x16x32_f16(
                        af[mi], bf[nj], acc[mi][nj], 0, 0, 0);
        }
    }
#undef LOADREGS

    float bb4[4];
#pragma unroll
    for (int nj = 0; nj < 4; nj++) bb4[nj] = bias[j0 + wc * 64 + nj * 16 + l15];
    const int hh = (j0 >> 6) + wc;             // head 0..15

    if (sel == 2) {
#pragma unroll
        for (int mi = 0; mi < 4; mi++)
#pragma unroll
            for (int r = 0; r < 4; r++) {
                int n = n0 + wr * 64 + mi * 16 + 4 * g + r;
                int b = n >> 11, t = n & (TT - 1);
                size_t rowbase = ((size_t)(b * HH + hh) * TT + t) << 6;
#pragma unroll
                for (int nj = 0; nj < 4; nj++) {
                    int dd = nj * 16 + l15;
                    outp[rowbase + dd] = f2h(acc[mi][nj][r] + bb4[nj]);
                }
            }
    } else {
#pragma unroll
        for (int mi = 0; mi < 4; mi++)
#pragma unroll
            for (int r = 0; r < 4; r++) {
                int n = n0 + wr * 64 + mi * 16 + 4 * g + r;
                int b = n >> 11, t = n & (TT - 1);
                size_t rowbase = ((size_t)(b * HH + hh) * TT + t) << 6;
                const float2* tp = tab + t * 32 + l15;
#pragma unroll
                for (int p = 0; p < 2; p++) {
                    float2 cs = tp[p * 16];
                    float x1 = acc[mi][p][r]     + bb4[p];
                    float x2 = acc[mi][p + 2][r] + bb4[p + 2];
                    int i = p * 16 + l15;
                    outp[rowbase + i]      = f2h(x1 * cs.x - x2 * cs.y);
                    outp[rowbase + i + 32] = f2h(x2 * cs.x + x1 * cs.y);
                }
            }
    }
}

// ---------------------------------------------------------------------------
// MFMA f16 GEMM for O-projection (verified R2 structure + XCD swizzle).
// ---------------------------------------------------------------------------
__global__ __launch_bounds__(256) void gemm_h(
    const unsigned short* __restrict__ A, const unsigned short* __restrict__ W,
    const float* __restrict__ bias, float* __restrict__ outp,
    int N, int K, int J)
{
    __shared__ __align__(16) unsigned short As[128 * 64];
    __shared__ __align__(16) unsigned short Ws[128 * 64];

    int total = gridDim.x * gridDim.y;
    int flat = blockIdx.y * gridDim.x + blockIdx.x;
    int swz = (flat & 7) * (total >> 3) + (flat >> 3);
    int bxi = swz % gridDim.x, byi = swz / gridDim.x;

    const int tid = threadIdx.x;
    const int w = tid >> 6, lane = tid & 63;
    const int l15 = lane & 15, g = lane >> 4;
    const int wr = w >> 1, wc = w & 1;
    const int n0 = byi * 128;
    const int j0 = bxi * 128;

    f32x4 acc[4][4];
#pragma unroll
    for (int mi = 0; mi < 4; mi++)
#pragma unroll
        for (int nj = 0; nj < 4; nj++) acc[mi][nj] = (f32x4){0.f, 0.f, 0.f, 0.f};

    u32x4 pa[4], pb[4];
#define LOADREGS(KS)                                                          \
    {                                                                         \
        _Pragma("unroll")                                                     \
        for (int it = 0; it < 4; it++) {                                      \
            int ci = tid + it * 256;                                          \
            int r = ci >> 3, p = ci & 7;                                      \
            pa[it] = *(const u32x4*)(A + (size_t)(n0 + r) * K + (KS) + p * 8);\
            pb[it] = *(const u32x4*)(W + (size_t)(j0 + r) * K + (KS) + p * 8);\
        }                                                                     \
    }

    LOADREGS(0)

    for (int ks = 0; ks < K; ks += 64) {
        __syncthreads();
#pragma unroll
        for (int it = 0; it < 4; it++) {
            int ci = tid + it * 256;
            int r = ci >> 3, p = ci & 7;
            int d = r * 64 + ((p ^ (r & 7)) << 3);
            *(u32x4*)(As + d) = pa[it];
            *(u32x4*)(Ws + d) = pb[it];
        }
        __syncthreads();
        if (ks + 64 < K) LOADREGS(ks + 64)

#pragma unroll
        for (int c = 0; c < 2; c++) {
            f16x8 af[4], bf[4];
            const int q0c = c * 4 + (g >> 1);
            const int q1c = q0c + 2;
            const int off = (g & 1) << 2;
#pragma unroll
            for (int mi = 0; mi < 4; mi++) {
                int r = wr * 64 + mi * 16 + l15;
                int sw = r & 7;
                const unsigned short* rp = As + r * 64;
                u32x2 x0 = *(const u32x2*)(rp + ((q0c ^ sw) << 3) + off);
                u32x2 x1 = *(const u32x2*)(rp + ((q1c ^ sw) << 3) + off);
                u32x4 uu = {x0.x, x0.y, x1.x, x1.y};
                af[mi] = __builtin_bit_cast(f16x8, uu);
            }
#pragma unroll
            for (int nj = 0; nj < 4; nj++) {
                int r = wc * 64 + nj * 16 + l15;
                int sw = r & 7;
                const unsigned short* rp = Ws + r * 64;
                u32x2 x0 = *(const u32x2*)(rp + ((q0c ^ sw) << 3) + off);
                u32x2 x1 = *(const u32x2*)(rp + ((q1c ^ sw) << 3) + off);
                u32x4 uu = {x0.x, x0.y, x1.x, x1.y};
                bf[nj] = __builtin_bit_cast(f16x8, uu);
            }
#pragma unroll
            for (int mi = 0; mi < 4; mi++)
#pragma unroll
                for (int nj = 0; nj < 4; nj++)
                    acc[mi][nj] = __builtin_amdgcn_mfma_f32_16x16x32_f16(
                        af[mi], bf[nj], acc[mi][nj], 0, 0, 0);
        }
    }
#undef LOADREGS

#pragma unroll
    for (int nj = 0; nj < 4; nj++) {
        int j = j0 + wc * 64 + nj * 16 + l15;
        float bb = bias[j];
#pragma unroll
        for (int mi = 0; mi < 4; mi++)
#pragma unroll
            for (int r = 0; r < 4; r++) {
                int n = n0 + wr * 64 + mi * 16 + 4 * g + r;
                outp[(size_t)n * J + j] = acc[mi][nj][r] + bb;
            }
    }
}

// ---------------------------------------------------------------------------
// MFMA flash attention (f16) — VERIFIED R4/R6 single-strip kernel, verbatim.
// Grid (16, H, B); block = 4 waves; q-tile pair (x, 31-x), 64 rows each.
// ---------------------------------------------------------------------------
__device__ __forceinline__ u32x2 ds_tr16(const unsigned short* p) {
    u32x2 r;
    asm volatile("ds_read_b64_tr_b16 %0, %1"
                 : "=v"(r)
                 : "v"((unsigned int)(unsigned long long)p));
    return r;
}

__global__ __launch_bounds__(256, 4) void attn_mfma(
    const unsigned short* __restrict__ q,
    const unsigned short* __restrict__ k,
    const unsigned short* __restrict__ v,
    unsigned short* __restrict__ aout)
{
    __shared__ __align__(16) unsigned short Ks[64 * 64];   // swizzled [key][dim]
    __shared__ __align__(16) unsigned short Vs[4 * 1056];  // [db][key][16]

    const int h = blockIdx.y, b = blockIdx.z;
    const int tid = threadIdx.x;
    const int w = tid >> 6;
    const int lane = tid & 63;
    const int l15 = lane & 15, g = lane >> 4;
    const int bh = b * HH + h;
    const size_t base = (size_t)bh * TT * 64;
    const unsigned short* Qp = q + base;
    const unsigned short* Kp = k + base;
    const unsigned short* Vp = v + base;

    const float SC = 0.18033688011112042f;   // log2(e)/8

    u32x4 kreg[2];
    u32x2 vreg[4];
#define LOADKV(KB)                                                             \
    {                                                                          \
        _Pragma("unroll")                                                      \
        for (int it = 0; it < 2; it++) {                                       \
            int vi = tid + it * 256;                                           \
            int key = vi >> 3, pr = vi & 7;                                    \
            kreg[it] = *(const u32x4*)(Kp + (size_t)((KB) + key) * 64 + pr * 8);\
        }                                                                      \
        _Pragma("unroll")                                                      \
        for (int it = 0; it < 4; it++) {                                       \
            int vi = tid + it * 256;                                           \
            int key = vi >> 4, c4 = vi & 15;                                   \
            vreg[it] = *(const u32x2*)(Vp + (size_t)((KB) + key) * 64 + c4 * 4);\
        }                                                                      \
    }

    for (int ph = 0; ph < 2; ph++) {
        const int qt = ph ? (31 - (int)blockIdx.x) : (int)blockIdx.x;
        const int q0 = qt * 64;

        f16x8 qf[2];
        {
            const unsigned short* Qr = Qp + (size_t)(q0 + w * 16 + l15) * 64;
#pragma unroll
            for (int c = 0; c < 2; c++) {
                u32x2 a0 = *(const u32x2*)(Qr + 32 * c + 4 * g);
                u32x2 a1 = *(const u32x2*)(Qr + 32 * c + 16 + 4 * g);
                u32x4 uu = {a0.x, a0.y, a1.x, a1.y};
                qf[c] = __builtin_bit_cast(f16x8, uu);
            }
        }

        float mrow = -1e30f, lrow = 0.f;
        f32x4 accO[4];
#pragma unroll
        for (int nb = 0; nb < 4; nb++) accO[nb] = (f32x4){0.f, 0.f, 0.f, 0.f};

        const int ntiles = qt + 1;
        LOADKV(0)

        for (int kt = 0; kt < ntiles; kt++) {
            const bool diag = (kt == qt);
            __syncthreads();
#pragma unroll
            for (int it = 0; it < 2; it++) {
                int vi = tid + it * 256;
                int key = vi >> 3, pr = vi & 7;
                *(u32x4*)(Ks + key * 64 + ((pr ^ (key & 7)) << 3)) = kreg[it];
            }
#pragma unroll
            for (int it = 0; it < 4; it++) {
                int vi = tid + it * 256;
                int key = vi >> 4, c4 = vi & 15;
                *(u32x2*)(Vs + (c4 >> 2) * 1056 + key * 16 + (c4 & 3) * 4) = vreg[it];
            }
            __syncthreads();
            if (kt + 1 < ntiles) LOADKV((kt + 1) * 64)

            const int nkb = diag ? (w + 1) : 4;
            f32x4 accS[4];
#pragma unroll
            for (int kb = 0; kb < 4; kb++) accS[kb] = (f32x4){0.f, 0.f, 0.f, 0.f};
            __builtin_amdgcn_s_setprio(1);
#pragma unroll
            for (int kb = 0; kb < 4; kb++) {
                if (kb < nkb) {
                    int key = kb * 16 + l15;
                    int sw = key & 7;
#pragma unroll
                    for (int c = 0; c < 2; c++) {
                        int c8a = 8 * c + g, c8b = 8 * c + 4 + g;
                        u32x2 x0 = *(const u32x2*)(Ks + key * 64 +
                                       (((c8a >> 1) ^ sw) << 3) + ((c8a & 1) << 2));
                        u32x2 x1 = *(const u32x2*)(Ks + key * 64 +
                                       (((c8b >> 1) ^ sw) << 3) + ((c8b & 1) << 2));
                        u32x4 uu = {x0.x, x0.y, x1.x, x1.y};
                        accS[kb] = __builtin_amdgcn_mfma_f32_16x16x32_f16(
                            __builtin_bit_cast(f16x8, uu), qf[c], accS[kb], 0, 0, 0);
                    }
                }
            }
            __builtin_amdgcn_s_setprio(0);

            float sloc[16];
            float tmax = -1e30f;
            if (diag) {
#pragma unroll
                for (int kb = 0; kb < 4; kb++)
#pragma unroll
                    for (int r = 0; r < 4; r++) {
                        float s = accS[kb][r];
                        bool valid = (kb * 16 + 4 * g + r <= w * 16 + l15);
                        s = valid ? s : -1e30f;
                        sloc[kb * 4 + r] = s;
                        tmax = fmaxf(tmax, s);
                    }
            } else {
#pragma unroll
                for (int kb = 0; kb < 4; kb++)
#pragma unroll
                    for (int r = 0; r < 4; r++) {
                        float s = accS[kb][r];
                        sloc[kb * 4 + r] = s;
                        tmax = fmaxf(tmax, s);
                    }
            }
            tmax = fmaxf(tmax, __shfl_xor(tmax, 16));
            tmax = fmaxf(tmax, __shfl_xor(tmax, 32));

            if (!__all(tmax - mrow <= 61.0f)) {     // 61*SC = 11 log2-units
                float mnew = fmaxf(mrow, tmax);
                float sf = exp2f((mrow - mnew) * SC);
                mrow = mnew;
                lrow *= sf;
                float sfr[4];
#pragma unroll
                for (int r = 0; r < 4; r++) sfr[r] = __shfl(sf, 4 * g + r);
#pragma unroll
                for (int nb = 0; nb < 4; nb++)
#pragma unroll
                    for (int r = 0; r < 4; r++) accO[nb][r] *= sfr[r];
            }

            const float nmsc = -mrow * SC;
            unsigned int pw[8];
            float psum = 0.f;
#pragma unroll
            for (int i = 0; i < 8; i++) {
                float p0 = exp2f(fmaf(sloc[2 * i],     SC, nmsc));
                float p1 = exp2f(fmaf(sloc[2 * i + 1], SC, nmsc));
                pw[i] = pkrtz(p0, p1);
                psum += p0 + p1;
            }
            psum += __shfl_xor(psum, 16);
            psum += __shfl_xor(psum, 32);
            lrow += psum;

            const int nkc = (diag && w < 2) ? 1 : 2;
#pragma unroll
            for (int kc = 0; kc < 2; kc++)
                if (kc < nkc) {
                    u32x2 vfr[4][2];
#pragma unroll
                    for (int nb = 0; nb < 4; nb++)
#pragma unroll
                        for (int t2 = 0; t2 < 2; t2++)
                            vfr[nb][t2] = ds_tr16(
                                Vs + nb * 1056 + (kc * 32 + 16 * t2) * 16 + 4 * lane);
                    asm volatile("s_waitcnt lgkmcnt(0)" ::: "memory");
                    __builtin_amdgcn_sched_barrier(0);
                    u32x4 pu = {pw[4 * kc + 0], pw[4 * kc + 1], pw[4 * kc + 2], pw[4 * kc + 3]};
                    f16x8 pf = __builtin_bit_cast(f16x8, pu);
                    __builtin_amdgcn_s_setprio(1);
#pragma unroll
                    for (int nb = 0; nb < 4; nb++) {
                        u32x4 vu = {vfr[nb][0].x, vfr[nb][0].y,
                                    vfr[nb][1].x, vfr[nb][1].y};
                        accO[nb] = __builtin_amdgcn_mfma_f32_16x16x32_f16(
                            pf, __builtin_bit_cast(f16x8, vu), accO[nb], 0, 0, 0);
                    }
                    __builtin_amdgcn_s_setprio(0);
                }
        }

        float linv = 1.0f / lrow;
        float sfr[4];
#pragma unroll
        for (int r = 0; r < 4; r++) sfr[r] = __shfl(linv, 4 * g + r);
#pragma unroll
        for (int r = 0; r < 4; r++) {
            int qr = q0 + w * 16 + 4 * g + r;
            unsigned short* orow = aout + (size_t)(b * TT + qr) * DD + h * 64;
#pragma unroll
            for (int nb = 0; nb < 4; nb++)
                orow[nb * 16 + l15] = f2h(accO[nb][r] * sfr[r]);
        }
    }
#undef LOADKV
}

// ---------------------------------------------------------------------------
extern "C" void kernel_launch(void* const* d_in, const int* in_sizes, int n_in,
                              void* d_out, int out_size, void* d_ws, size_t ws_size,
                              hipStream_t stream)
{
    const float* x  = (const float*)d_in[0];
    const float* Wq = (const float*)d_in[1];
    const float* bq = (const float*)d_in[2];
    const float* Wk = (const float*)d_in[3];
    const float* bk = (const float*)d_in[4];
    const float* Wv = (const float*)d_in[5];
    const float* bv = (const float*)d_in[6];
    const float* Wo = (const float*)d_in[7];
    const float* bo = (const float*)d_in[8];
    float* out = (float*)d_out;                     // FLOAT32 output [B,T,D]

    const size_t NE = (size_t)BB * HH * TT * HD;    // 8388608 elements
    // ws: q|k|v f16 contiguous. Direct mode (ws >= 67.1 MB): att f16 at
    // ws[3NE..4NE); Wo_h in dead q region; gemm_h -> d_out (no memcpy).
    // Fallback: att in d_out scratch, Wo_h in d_out after tab, gemm_h -> ws
    // res + memcpy (verified R6 structure).
    unsigned short* qkv  = (unsigned short*)d_ws;
    unsigned short* qb   = qkv;
    unsigned short* kbuf = qkv + NE;
    unsigned short* vbuf = qkv + 2 * NE;
    float* res = (float*)d_ws;                      // overlays dead q+k (fallback)

    // d_out scratch (all dead before the final result lands):
    //  elements [0 .. 8388608)         x_h f16 (fallback: att_h overlays)
    //  elements [8388608 .. 11534336)  wq|wk|wv f16
    //  elements [11534336 .. 11796480) rope table float2 [2048][32]
    //  elements [11796480 .. 12845056) Wo_h f16 (FALLBACK only)
    unsigned short* ds  = (unsigned short*)d_out;
    unsigned short* xh  = ds;
    unsigned short* wh  = ds + 8388608;
    float2* tab = (float2*)(ds + 11534336);

    const bool direct = ws_size >= (size_t)8 * NE;  // bytes: 4 f16 regions
    unsigned short* att = direct ? (qkv + 3 * NE) : ds;
    unsigned short* woh = direct ? (unsigned short*)d_ws : (ds + 11796480);
    float* resout = direct ? out : res;

    const int N = BB * TT;                          // 8192 tokens
    dim3 blk(256);

    // 1) convert x + Wq|Wk|Wv to f16, build rope table (single launch)
    conv_all<<<11520, blk, 0, stream>>>(
        (const float4*)x, (const float4*)Wq, (const float4*)Wk,
        (const float4*)Wv, (ushort4*)xh, (ushort4*)wh, tab);

    // 2) fused QKV projection + table RoPE (single launch, XCD-swizzled)
    gemm_qkv<<<1536, blk, 0, stream>>>(xh, wh, bq, bk, bv, tab, qkv);

    // 3) flash attention (verified single-strip) -> att f16
    attn_mfma<<<dim3(TT / 128, HH, BB), blk, 0, stream>>>(qb, kbuf, vbuf, att);

    // 4) convert Wo AFTER attn into a region gemm_h never writes
    conv_wo<<<1024, blk, 0, stream>>>((const float4*)Wo, (ushort4*)woh);

    // 5) O-projection -> f32 (direct: into d_out; fallback: ws res)
    gemm_h<<<dim3(DD / 128, N / 128), blk, 0, stream>>>(att, woh, bo, resout, N, DD, DD);

    // 6) fallback copy
    if (!direct)
        hipMemcpyAsync(out, res, (size_t)N * DD * sizeof(float),
                       hipMemcpyDeviceToDevice, stream);
}

// Round 10
// 286.815 us; speedup vs baseline: 1.8774x; 1.0915x over previous
//
#include <hip/hip_runtime.h>

// Problem constants: B=4, T=2048, D=1024, H=16, HD=64
// Math (certified r6): torch convention x@W.T+b, rotate-half RoPE pos=t+1,
// causal softmax(QK^T/8)V, O-proj. Output f32 [B,T,D].
// R10: attn QBLK=128 via 8 waves x 16 rows (512 threads). Per-wave body is
// the VERIFIED R4/R9 algebra verbatim (single m/l/accO per thread); only
// wave->tile mapping generalized: wd=w&3, wt=w>>2, dtile=2qs+wt; active
// iff kt<=dtile, diag iff kt==dtile, diag mask uses wd. K/V HBM traffic
// halved vs R9. Rest of pipeline = verified R9.
#define BB 4
#define TT 2048
#define DD 1024
#define HH 16
#define HD 64

typedef __attribute__((ext_vector_type(8))) _Float16 f16x8;
typedef __attribute__((ext_vector_type(4))) float f32x4;
typedef __attribute__((ext_vector_type(2))) unsigned int u32x2;
typedef __attribute__((ext_vector_type(4))) unsigned int u32x4;

__device__ __forceinline__ float h2f(unsigned short u) {
    return (float)__builtin_bit_cast(_Float16, u);
}
__device__ __forceinline__ unsigned short f2h(float f) {
    return __builtin_bit_cast(unsigned short, (_Float16)f);
}
__device__ __forceinline__ unsigned int pkrtz(float a, float b) {
    return __builtin_bit_cast(unsigned int, __builtin_amdgcn_cvt_pkrtz(a, b));
}

// ---------------------------------------------------------------------------
// Fused f32 -> f16 convert: x + Wq|Wk|Wv + RoPE (cos,sin) table.
// ---------------------------------------------------------------------------
__global__ __launch_bounds__(256) void conv_all(
    const float4* __restrict__ x,
    const float4* __restrict__ Wq, const float4* __restrict__ Wk,
    const float4* __restrict__ Wv,
    ushort4* __restrict__ xh, ushort4* __restrict__ wh,
    float2* __restrict__ tab)
{
    int vi = blockIdx.x * 256 + threadIdx.x;
    if (vi < 2097152) {
        float4 v = x[vi];
        xh[vi] = (ushort4){ f2h(v.x), f2h(v.y), f2h(v.z), f2h(v.w) };
    } else if (vi < 2883584) {
        int u = vi - 2097152;               // [0, 786432)
        int w = u >> 18;                    // 0..2 (uniform per block)
        const float4* src = (w == 0) ? Wq : (w == 1) ? Wk : Wv;
        float4 v = src[u & 262143];
        wh[u] = (ushort4){ f2h(v.x), f2h(v.y), f2h(v.z), f2h(v.w) };
    } else {
        int u = vi - 2883584;               // [0, 65536): (t, i)
        int t = u >> 5, i = u & 31;
        float ang = (float)(t + 1) *
                    exp2f(-(float)i * (13.287712379549449f / 32.0f));
        tab[u] = (float2){ cosf(ang), sinf(ang) };
    }
}

// Wo f32 -> f16 (launched AFTER attn; dst never aliased with gemm_h writes).
__global__ __launch_bounds__(256) void conv_wo(
    const float4* __restrict__ Wo, ushort4* __restrict__ dst)
{
    int i = blockIdx.x * 256 + threadIdx.x;   // 262144 total
    float4 v = Wo[i];
    dst[i] = (ushort4){ f2h(v.x), f2h(v.y), f2h(v.z), f2h(v.w) };
}

// ---------------------------------------------------------------------------
// Fused QKV MFMA GEMM + table-based RoPE epilogue (verified R6, unchanged).
// ---------------------------------------------------------------------------
__global__ __launch_bounds__(256) void gemm_qkv(
    const unsigned short* __restrict__ A,      // x_h [8192][1024]
    const unsigned short* __restrict__ Wall,   // wq|wk|wv f16 [3][1024][1024]
    const float* __restrict__ bq, const float* __restrict__ bk,
    const float* __restrict__ bv,
    const float2* __restrict__ tab,            // [2048][32] (cos,sin)
    unsigned short* __restrict__ qkv)          // q|k|v f16 [3][B,H,T,64]
{
    __shared__ __align__(16) unsigned short As[128 * 64];
    __shared__ __align__(16) unsigned short Ws[128 * 64];

    int bid = blockIdx.x;
    int swz = (bid & 7) * 192 + (bid >> 3);
    int bx = swz % 24, by = swz / 24;
    const int sel = bx >> 3;                   // 0=q 1=k 2=v
    const int jb = bx & 7;
    const int n0 = by * 128;
    const int j0 = jb * 128;

    const unsigned short* W = Wall + (size_t)sel * 1048576;
    const float* bias = (sel == 0) ? bq : (sel == 1) ? bk : bv;
    unsigned short* outp = qkv + (size_t)sel * (BB * HH * TT * HD);

    const int tid = threadIdx.x;
    const int w = tid >> 6, lane = tid & 63;
    const int l15 = lane & 15, g = lane >> 4;
    const int wr = w >> 1, wc = w & 1;

    f32x4 acc[4][4];
#pragma unroll
    for (int mi = 0; mi < 4; mi++)
#pragma unroll
        for (int nj = 0; nj < 4; nj++) acc[mi][nj] = (f32x4){0.f, 0.f, 0.f, 0.f};

    u32x4 pa[4], pb[4];
#define LOADREGS(KS)                                                             \
    {                                                                            \
        _Pragma("unroll")                                                        \
        for (int it = 0; it < 4; it++) {                                         \
            int ci = tid + it * 256;                                             \
            int r = ci >> 3, p = ci & 7;                                         \
            pa[it] = *(const u32x4*)(A + (size_t)(n0 + r) * 1024 + (KS) + p * 8);\
            pb[it] = *(const u32x4*)(W + (size_t)(j0 + r) * 1024 + (KS) + p * 8);\
        }                                                                        \
    }

    LOADREGS(0)

    for (int ks = 0; ks < 1024; ks += 64) {
        __syncthreads();
#pragma unroll
        for (int it = 0; it < 4; it++) {
            int ci = tid + it * 256;
            int r = ci >> 3, p = ci & 7;
            int d = r * 64 + ((p ^ (r & 7)) << 3);
            *(u32x4*)(As + d) = pa[it];
            *(u32x4*)(Ws + d) = pb[it];
        }
        __syncthreads();
        if (ks + 64 < 1024) LOADREGS(ks + 64)

#pragma unroll
        for (int c = 0; c < 2; c++) {
            f16x8 af[4], bf[4];
            const int q0c = c * 4 + (g >> 1);
            const int q1c = q0c + 2;
            const int off = (g & 1) << 2;
#pragma unroll
            for (int mi = 0; mi < 4; mi++) {
                int r = wr * 64 + mi * 16 + l15;
                int sw = r & 7;
                const unsigned short* rp = As + r * 64;
                u32x2 x0 = *(const u32x2*)(rp + ((q0c ^ sw) << 3) + off);
                u32x2 x1 = *(const u32x2*)(rp + ((q1c ^ sw) << 3) + off);
                u32x4 uu = {x0.x, x0.y, x1.x, x1.y};
                af[mi] = __builtin_bit_cast(f16x8, uu);
            }
#pragma unroll
            for (int nj = 0; nj < 4; nj++) {
                int r = wc * 64 + nj * 16 + l15;
                int sw = r & 7;
                const unsigned short* rp = Ws + r * 64;
                u32x2 x0 = *(const u32x2*)(rp + ((q0c ^ sw) << 3) + off);
                u32x2 x1 = *(const u32x2*)(rp + ((q1c ^ sw) << 3) + off);
                u32x4 uu = {x0.x, x0.y, x1.x, x1.y};
                bf[nj] = __builtin_bit_cast(f16x8, uu);
            }
#pragma unroll
            for (int mi = 0; mi < 4; mi++)
#pragma unroll
                for (int nj = 0; nj < 4; nj++)
                    acc[mi][nj] = __builtin_amdgcn_mfma_f32_16x16x32_f16(
                        af[mi], bf[nj], acc[mi][nj], 0, 0, 0);
        }
    }
#undef LOADREGS

    float bb4[4];
#pragma unroll
    for (int nj = 0; nj < 4; nj++) bb4[nj] = bias[j0 + wc * 64 + nj * 16 + l15];
    const int hh = (j0 >> 6) + wc;             // head 0..15

    if (sel == 2) {
#pragma unroll
        for (int mi = 0; mi < 4; mi++)
#pragma unroll
            for (int r = 0; r < 4; r++) {
                int n = n0 + wr * 64 + mi * 16 + 4 * g + r;
                int b = n >> 11, t = n & (TT - 1);
                size_t rowbase = ((size_t)(b * HH + hh) * TT + t) << 6;
#pragma unroll
                for (int nj = 0; nj < 4; nj++) {
                    int dd = nj * 16 + l15;
                    outp[rowbase + dd] = f2h(acc[mi][nj][r] + bb4[nj]);
                }
            }
    } else {
#pragma unroll
        for (int mi = 0; mi < 4; mi++)
#pragma unroll
            for (int r = 0; r < 4; r++) {
                int n = n0 + wr * 64 + mi * 16 + 4 * g + r;
                int b = n >> 11, t = n & (TT - 1);
                size_t rowbase = ((size_t)(b * HH + hh) * TT + t) << 6;
                const float2* tp = tab + t * 32 + l15;
#pragma unroll
                for (int p = 0; p < 2; p++) {
                    float2 cs = tp[p * 16];
                    float x1 = acc[mi][p][r]     + bb4[p];
                    float x2 = acc[mi][p + 2][r] + bb4[p + 2];
                    int i = p * 16 + l15;
                    outp[rowbase + i]      = f2h(x1 * cs.x - x2 * cs.y);
                    outp[rowbase + i + 32] = f2h(x2 * cs.x + x1 * cs.y);
                }
            }
    }
}

// ---------------------------------------------------------------------------
// MFMA f16 GEMM for O-projection (verified R2 structure + XCD swizzle).
// ---------------------------------------------------------------------------
__global__ __launch_bounds__(256) void gemm_h(
    const unsigned short* __restrict__ A, const unsigned short* __restrict__ W,
    const float* __restrict__ bias, float* __restrict__ outp,
    int N, int K, int J)
{
    __shared__ __align__(16) unsigned short As[128 * 64];
    __shared__ __align__(16) unsigned short Ws[128 * 64];

    int total = gridDim.x * gridDim.y;
    int flat = blockIdx.y * gridDim.x + blockIdx.x;
    int swz = (flat & 7) * (total >> 3) + (flat >> 3);
    int bxi = swz % gridDim.x, byi = swz / gridDim.x;

    const int tid = threadIdx.x;
    const int w = tid >> 6, lane = tid & 63;
    const int l15 = lane & 15, g = lane >> 4;
    const int wr = w >> 1, wc = w & 1;
    const int n0 = byi * 128;
    const int j0 = bxi * 128;

    f32x4 acc[4][4];
#pragma unroll
    for (int mi = 0; mi < 4; mi++)
#pragma unroll
        for (int nj = 0; nj < 4; nj++) acc[mi][nj] = (f32x4){0.f, 0.f, 0.f, 0.f};

    u32x4 pa[4], pb[4];
#define LOADREGS(KS)                                                          \
    {                                                                         \
        _Pragma("unroll")                                                     \
        for (int it = 0; it < 4; it++) {                                      \
            int ci = tid + it * 256;                                          \
            int r = ci >> 3, p = ci & 7;                                      \
            pa[it] = *(const u32x4*)(A + (size_t)(n0 + r) * K + (KS) + p * 8);\
            pb[it] = *(const u32x4*)(W + (size_t)(j0 + r) * K + (KS) + p * 8);\
        }                                                                     \
    }

    LOADREGS(0)

    for (int ks = 0; ks < K; ks += 64) {
        __syncthreads();
#pragma unroll
        for (int it = 0; it < 4; it++) {
            int ci = tid + it * 256;
            int r = ci >> 3, p = ci & 7;
            int d = r * 64 + ((p ^ (r & 7)) << 3);
            *(u32x4*)(As + d) = pa[it];
            *(u32x4*)(Ws + d) = pb[it];
        }
        __syncthreads();
        if (ks + 64 < K) LOADREGS(ks + 64)

#pragma unroll
        for (int c = 0; c < 2; c++) {
            f16x8 af[4], bf[4];
            const int q0c = c * 4 + (g >> 1);
            const int q1c = q0c + 2;
            const int off = (g & 1) << 2;
#pragma unroll
            for (int mi = 0; mi < 4; mi++) {
                int r = wr * 64 + mi * 16 + l15;
                int sw = r & 7;
                const unsigned short* rp = As + r * 64;
                u32x2 x0 = *(const u32x2*)(rp + ((q0c ^ sw) << 3) + off);
                u32x2 x1 = *(const u32x2*)(rp + ((q1c ^ sw) << 3) + off);
                u32x4 uu = {x0.x, x0.y, x1.x, x1.y};
                af[mi] = __builtin_bit_cast(f16x8, uu);
            }
#pragma unroll
            for (int nj = 0; nj < 4; nj++) {
                int r = wc * 64 + nj * 16 + l15;
                int sw = r & 7;
                const unsigned short* rp = Ws + r * 64;
                u32x2 x0 = *(const u32x2*)(rp + ((q0c ^ sw) << 3) + off);
                u32x2 x1 = *(const u32x2*)(rp + ((q1c ^ sw) << 3) + off);
                u32x4 uu = {x0.x, x0.y, x1.x, x1.y};
                bf[nj] = __builtin_bit_cast(f16x8, uu);
            }
#pragma unroll
            for (int mi = 0; mi < 4; mi++)
#pragma unroll
                for (int nj = 0; nj < 4; nj++)
                    acc[mi][nj] = __builtin_amdgcn_mfma_f32_16x16x32_f16(
                        af[mi], bf[nj], acc[mi][nj], 0, 0, 0);
        }
    }
#undef LOADREGS

#pragma unroll
    for (int nj = 0; nj < 4; nj++) {
        int j = j0 + wc * 64 + nj * 16 + l15;
        float bb = bias[j];
#pragma unroll
        for (int mi = 0; mi < 4; mi++)
#pragma unroll
            for (int r = 0; r < 4; r++) {
                int n = n0 + wr * 64 + mi * 16 + 4 * g + r;
                outp[(size_t)n * J + j] = acc[mi][nj][r] + bb;
            }
    }
}

// ---------------------------------------------------------------------------
// MFMA flash attention (f16), R10: 8 waves x 16 rows = QBLK 128.
// Grid (8, H, B) = 512 blocks x 512 threads; q-tile pair (x, 15-x) -> 34
// uniform KV tiles/block. Wave w: wd=w&3, wt=w>>2, dtile=2qs+wt; active
// iff kt<=dtile, diag iff kt==dtile (mask uses wd). Per-wave body verbatim
// verified R4/R9 algebra; inactive waves skip compute but hit barriers.
// ---------------------------------------------------------------------------
__device__ __forceinline__ u32x2 ds_tr16(const unsigned short* p) {
    u32x2 r;
    asm volatile("ds_read_b64_tr_b16 %0, %1"
                 : "=v"(r)
                 : "v"((unsigned int)(unsigned long long)p));
    return r;
}

__global__ __launch_bounds__(512, 4) void attn_mfma(
    const unsigned short* __restrict__ q,
    const unsigned short* __restrict__ k,
    const unsigned short* __restrict__ v,
    unsigned short* __restrict__ aout)
{
    __shared__ __align__(16) unsigned short Ks[64 * 64];   // swizzled [key][dim]
    __shared__ __align__(16) unsigned short Vs[4 * 1056];  // [db][key][16]

    const int h = blockIdx.y, b = blockIdx.z;
    const int tid = threadIdx.x;
    const int w = tid >> 6;              // wave 0..7
    const int wd = w & 3;
    const int wt = w >> 2;               // which 64-row half of the 128 block
    const int lane = tid & 63;
    const int l15 = lane & 15, g = lane >> 4;
    const int bh = b * HH + h;
    const size_t base = (size_t)bh * TT * 64;
    const unsigned short* Qp = q + base;
    const unsigned short* Kp = k + base;
    const unsigned short* Vp = v + base;

    const float SC = 0.18033688011112042f;   // log2(e)/8

    u32x4 kreg;
    u32x2 vreg[2];
#define LOADKV(KB)                                                             \
    {                                                                          \
        {                                                                      \
            int key = tid >> 3, pr = tid & 7;                                  \
            kreg = *(const u32x4*)(Kp + (size_t)((KB) + key) * 64 + pr * 8);   \
        }                                                                      \
        _Pragma("unroll")                                                      \
        for (int it = 0; it < 2; it++) {                                       \
            int vi = tid + it * 512;                                           \
            int key = vi >> 4, c4 = vi & 15;                                   \
            vreg[it] = *(const u32x2*)(Vp + (size_t)((KB) + key) * 64 + c4 * 4);\
        }                                                                      \
    }

    for (int ph = 0; ph < 2; ph++) {
        const int qs = ph ? (15 - (int)blockIdx.x) : (int)blockIdx.x;
        const int q0 = qs * 128;
        const int dtile = 2 * qs + wt;

        f16x8 qf[2];
        {
            const unsigned short* Qr = Qp + (size_t)(q0 + w * 16 + l15) * 64;
#pragma unroll
            for (int c = 0; c < 2; c++) {
                u32x2 a0 = *(const u32x2*)(Qr + 32 * c + 4 * g);
                u32x2 a1 = *(const u32x2*)(Qr + 32 * c + 16 + 4 * g);
                u32x4 uu = {a0.x, a0.y, a1.x, a1.y};
                qf[c] = __builtin_bit_cast(f16x8, uu);
            }
        }

        float mrow = -1e30f, lrow = 0.f;
        f32x4 accO[4];
#pragma unroll
        for (int nb = 0; nb < 4; nb++) accO[nb] = (f32x4){0.f, 0.f, 0.f, 0.f};

        const int ntiles = 2 * qs + 2;
        LOADKV(0)

        for (int kt = 0; kt < ntiles; kt++) {
            const bool active = (kt <= dtile);
            const bool diag = (kt == dtile);
            __syncthreads();
            // ---- stage (all 512 threads), verbatim formulas
            {
                int key = tid >> 3, pr = tid & 7;
                *(u32x4*)(Ks + key * 64 + ((pr ^ (key & 7)) << 3)) = kreg;
            }
#pragma unroll
            for (int it = 0; it < 2; it++) {
                int vi = tid + it * 512;
                int key = vi >> 4, c4 = vi & 15;
                *(u32x2*)(Vs + (c4 >> 2) * 1056 + key * 16 + (c4 & 3) * 4) = vreg[it];
            }
            __syncthreads();
            if (kt + 1 < ntiles) LOADKV((kt + 1) * 64)

            if (active) {
                const int nkb = diag ? (wd + 1) : 4;
                f32x4 accS[4];
#pragma unroll
                for (int kb = 0; kb < 4; kb++) accS[kb] = (f32x4){0.f, 0.f, 0.f, 0.f};
                __builtin_amdgcn_s_setprio(1);
#pragma unroll
                for (int kb = 0; kb < 4; kb++) {
                    if (kb < nkb) {
                        int key = kb * 16 + l15;
                        int sw = key & 7;
#pragma unroll
                        for (int c = 0; c < 2; c++) {
                            int c8a = 8 * c + g, c8b = 8 * c + 4 + g;
                            u32x2 x0 = *(const u32x2*)(Ks + key * 64 +
                                           (((c8a >> 1) ^ sw) << 3) + ((c8a & 1) << 2));
                            u32x2 x1 = *(const u32x2*)(Ks + key * 64 +
                                           (((c8b >> 1) ^ sw) << 3) + ((c8b & 1) << 2));
                            u32x4 uu = {x0.x, x0.y, x1.x, x1.y};
                            accS[kb] = __builtin_amdgcn_mfma_f32_16x16x32_f16(
                                __builtin_bit_cast(f16x8, uu), qf[c], accS[kb], 0, 0, 0);
                        }
                    }
                }
                __builtin_amdgcn_s_setprio(0);

                float sloc[16];
                float tmax = -1e30f;
                if (diag) {
#pragma unroll
                    for (int kb = 0; kb < 4; kb++)
#pragma unroll
                        for (int r = 0; r < 4; r++) {
                            float s = accS[kb][r];
                            bool valid = (kb * 16 + 4 * g + r <= wd * 16 + l15);
                            s = valid ? s : -1e30f;
                            sloc[kb * 4 + r] = s;
                            tmax = fmaxf(tmax, s);
                        }
                } else {
#pragma unroll
                    for (int kb = 0; kb < 4; kb++)
#pragma unroll
                        for (int r = 0; r < 4; r++) {
                            float s = accS[kb][r];
                            sloc[kb * 4 + r] = s;
                            tmax = fmaxf(tmax, s);
                        }
                }
                tmax = fmaxf(tmax, __shfl_xor(tmax, 16));
                tmax = fmaxf(tmax, __shfl_xor(tmax, 32));

                if (!__all(tmax - mrow <= 61.0f)) {     // 61*SC = 11 log2-units
                    float mnew = fmaxf(mrow, tmax);
                    float sf = exp2f((mrow - mnew) * SC);
                    mrow = mnew;
                    lrow *= sf;
                    float sfr[4];
#pragma unroll
                    for (int r = 0; r < 4; r++) sfr[r] = __shfl(sf, 4 * g + r);
#pragma unroll
                    for (int nb = 0; nb < 4; nb++)
#pragma unroll
                        for (int r = 0; r < 4; r++) accO[nb][r] *= sfr[r];
                }

                const float nmsc = -mrow * SC;
                unsigned int pw[8];
                float psum = 0.f;
#pragma unroll
                for (int i = 0; i < 8; i++) {
                    float p0 = exp2f(fmaf(sloc[2 * i],     SC, nmsc));
                    float p1 = exp2f(fmaf(sloc[2 * i + 1], SC, nmsc));
                    pw[i] = pkrtz(p0, p1);
                    psum += p0 + p1;
                }
                psum += __shfl_xor(psum, 16);
                psum += __shfl_xor(psum, 32);
                lrow += psum;

                const int nkc = (diag && wd < 2) ? 1 : 2;
#pragma unroll
                for (int kc = 0; kc < 2; kc++)
                    if (kc < nkc) {
                        u32x2 vfr[4][2];
#pragma unroll
                        for (int nb = 0; nb < 4; nb++)
#pragma unroll
                            for (int t2 = 0; t2 < 2; t2++)
                                vfr[nb][t2] = ds_tr16(
                                    Vs + nb * 1056 + (kc * 32 + 16 * t2) * 16 + 4 * lane);
                        asm volatile("s_waitcnt lgkmcnt(0)" ::: "memory");
                        __builtin_amdgcn_sched_barrier(0);
                        u32x4 pu = {pw[4 * kc + 0], pw[4 * kc + 1], pw[4 * kc + 2], pw[4 * kc + 3]};
                        f16x8 pf = __builtin_bit_cast(f16x8, pu);
                        __builtin_amdgcn_s_setprio(1);
#pragma unroll
                        for (int nb = 0; nb < 4; nb++) {
                            u32x4 vu = {vfr[nb][0].x, vfr[nb][0].y,
                                        vfr[nb][1].x, vfr[nb][1].y};
                            accO[nb] = __builtin_amdgcn_mfma_f32_16x16x32_f16(
                                pf, __builtin_bit_cast(f16x8, vu), accO[nb], 0, 0, 0);
                        }
                        __builtin_amdgcn_s_setprio(0);
                    }
            }
        }

        float linv = 1.0f / lrow;
        float sfr[4];
#pragma unroll
        for (int r = 0; r < 4; r++) sfr[r] = __shfl(linv, 4 * g + r);
#pragma unroll
        for (int r = 0; r < 4; r++) {
            int qr = q0 + w * 16 + 4 * g + r;
            unsigned short* orow = aout + (size_t)(b * TT + qr) * DD + h * 64;
#pragma unroll
            for (int nb = 0; nb < 4; nb++)
                orow[nb * 16 + l15] = f2h(accO[nb][r] * sfr[r]);
        }
    }
#undef LOADKV
}

// ---------------------------------------------------------------------------
extern "C" void kernel_launch(void* const* d_in, const int* in_sizes, int n_in,
                              void* d_out, int out_size, void* d_ws, size_t ws_size,
                              hipStream_t stream)
{
    const float* x  = (const float*)d_in[0];
    const float* Wq = (const float*)d_in[1];
    const float* bq = (const float*)d_in[2];
    const float* Wk = (const float*)d_in[3];
    const float* bk = (const float*)d_in[4];
    const float* Wv = (const float*)d_in[5];
    const float* bv = (const float*)d_in[6];
    const float* Wo = (const float*)d_in[7];
    const float* bo = (const float*)d_in[8];
    float* out = (float*)d_out;                     // FLOAT32 output [B,T,D]

    const size_t NE = (size_t)BB * HH * TT * HD;    // 8388608 elements
    // ws: q|k|v f16 contiguous. Direct mode (ws >= 67.1 MB): att f16 at
    // ws[3NE..4NE); Wo_h in dead q region; gemm_h -> d_out (no memcpy).
    // Fallback: att in d_out scratch, Wo_h in d_out after tab, gemm_h -> ws
    // res + memcpy (verified R6 structure).
    unsigned short* qkv  = (unsigned short*)d_ws;
    unsigned short* qb   = qkv;
    unsigned short* kbuf = qkv + NE;
    unsigned short* vbuf = qkv + 2 * NE;
    float* res = (float*)d_ws;                      // overlays dead q+k (fallback)

    // d_out scratch (all dead before the final result lands):
    //  elements [0 .. 8388608)         x_h f16 (fallback: att_h overlays)
    //  elements [8388608 .. 11534336)  wq|wk|wv f16
    //  elements [11534336 .. 11796480) rope table float2 [2048][32]
    //  elements [11796480 .. 12845056) Wo_h f16 (FALLBACK only)
    unsigned short* ds  = (unsigned short*)d_out;
    unsigned short* xh  = ds;
    unsigned short* wh  = ds + 8388608;
    float2* tab = (float2*)(ds + 11534336);

    const bool direct = ws_size >= (size_t)8 * NE;  // bytes: 4 f16 regions
    unsigned short* att = direct ? (qkv + 3 * NE) : ds;
    unsigned short* woh = direct ? (unsigned short*)d_ws : (ds + 11796480);
    float* resout = direct ? out : res;

    const int N = BB * TT;                          // 8192 tokens
    dim3 blk(256);

    // 1) convert x + Wq|Wk|Wv to f16, build rope table (single launch)
    conv_all<<<11520, blk, 0, stream>>>(
        (const float4*)x, (const float4*)Wq, (const float4*)Wk,
        (const float4*)Wv, (ushort4*)xh, (ushort4*)wh, tab);

    // 2) fused QKV projection + table RoPE (single launch, XCD-swizzled)
    gemm_qkv<<<1536, blk, 0, stream>>>(xh, wh, bq, bk, bv, tab, qkv);

    // 3) flash attention (8-wave QBLK=128) -> att f16
    attn_mfma<<<dim3(8, HH, BB), dim3(512), 0, stream>>>(qb, kbuf, vbuf, att);

    // 4) convert Wo AFTER attn into a region gemm_h never writes
    conv_wo<<<1024, blk, 0, stream>>>((const float4*)Wo, (ushort4*)woh);

    // 5) O-projection -> f32 (direct: into d_out; fallback: ws res)
    gemm_h<<<dim3(DD / 128, N / 128), blk, 0, stream>>>(att, woh, bo, resout, N, DD, DD);

    // 6) fallback copy
    if (!direct)
        hipMemcpyAsync(out, res, (size_t)N * DD * sizeof(float),
                       hipMemcpyDeviceToDevice, stream);
}

// Round 11
// 283.904 us; speedup vs baseline: 1.8966x; 1.0103x over previous
//
#include <hip/hip_runtime.h>

// Problem constants: B=4, T=2048, D=1024, H=16, HD=64
// Math (certified r6): torch convention x@W.T+b, rotate-half RoPE pos=t+1,
// causal softmax(QK^T/8)V, O-proj. Output f32 [B,T,D].
// R11: GEMM staging via global_load_lds dwordx4 + double-buffered LDS
// (1 barrier/K-step). LDS dest linear; SOURCE chunk pre-swizzled p=pp^(r&7)
// (involution) so the verified swizzled read formulas are unchanged.
// attn = verified R10 8-wave QBLK=128; plumbing = verified R9.
#define BB 4
#define TT 2048
#define DD 1024
#define HH 16
#define HD 64

typedef __attribute__((ext_vector_type(8))) _Float16 f16x8;
typedef __attribute__((ext_vector_type(4))) float f32x4;
typedef __attribute__((ext_vector_type(2))) unsigned int u32x2;
typedef __attribute__((ext_vector_type(4))) unsigned int u32x4;

__device__ __forceinline__ float h2f(unsigned short u) {
    return (float)__builtin_bit_cast(_Float16, u);
}
__device__ __forceinline__ unsigned short f2h(float f) {
    return __builtin_bit_cast(unsigned short, (_Float16)f);
}
__device__ __forceinline__ unsigned int pkrtz(float a, float b) {
    return __builtin_bit_cast(unsigned int, __builtin_amdgcn_cvt_pkrtz(a, b));
}

// ---------------------------------------------------------------------------
// Fused f32 -> f16 convert: x + Wq|Wk|Wv + RoPE (cos,sin) table.
// ---------------------------------------------------------------------------
__global__ __launch_bounds__(256) void conv_all(
    const float4* __restrict__ x,
    const float4* __restrict__ Wq, const float4* __restrict__ Wk,
    const float4* __restrict__ Wv,
    ushort4* __restrict__ xh, ushort4* __restrict__ wh,
    float2* __restrict__ tab)
{
    int vi = blockIdx.x * 256 + threadIdx.x;
    if (vi < 2097152) {
        float4 v = x[vi];
        xh[vi] = (ushort4){ f2h(v.x), f2h(v.y), f2h(v.z), f2h(v.w) };
    } else if (vi < 2883584) {
        int u = vi - 2097152;               // [0, 786432)
        int w = u >> 18;                    // 0..2 (uniform per block)
        const float4* src = (w == 0) ? Wq : (w == 1) ? Wk : Wv;
        float4 v = src[u & 262143];
        wh[u] = (ushort4){ f2h(v.x), f2h(v.y), f2h(v.z), f2h(v.w) };
    } else {
        int u = vi - 2883584;               // [0, 65536): (t, i)
        int t = u >> 5, i = u & 31;
        float ang = (float)(t + 1) *
                    exp2f(-(float)i * (13.287712379549449f / 32.0f));
        tab[u] = (float2){ cosf(ang), sinf(ang) };
    }
}

// Wo f32 -> f16 (launched AFTER attn; dst never aliased with gemm_h writes).
__global__ __launch_bounds__(256) void conv_wo(
    const float4* __restrict__ Wo, ushort4* __restrict__ dst)
{
    int i = blockIdx.x * 256 + threadIdx.x;   // 262144 total
    float4 v = Wo[i];
    dst[i] = (ushort4){ f2h(v.x), f2h(v.y), f2h(v.z), f2h(v.w) };
}

// ---------------------------------------------------------------------------
// Staging: global_load_lds dwordx4, linear LDS dest (wave-uniform base +
// lane*16B), source chunk pre-swizzled p = pp ^ (r&7) (involution).
// Chunk ci = it*256 + tid: row r = ci>>3, LDS 16B-slot pp = ci&7.
// ---------------------------------------------------------------------------
#define GLDS(gp, lp)                                                          \
    __builtin_amdgcn_global_load_lds(                                         \
        (const __attribute__((address_space(1))) unsigned int*)(gp),          \
        (__attribute__((address_space(3))) unsigned int*)(lp), 16, 0, 0)

// ---------------------------------------------------------------------------
// Fused QKV MFMA GEMM + table RoPE epilogue. R11: gload_lds double-buffer.
// ---------------------------------------------------------------------------
__global__ __launch_bounds__(256) void gemm_qkv(
    const unsigned short* __restrict__ A,      // x_h [8192][1024]
    const unsigned short* __restrict__ Wall,   // wq|wk|wv f16 [3][1024][1024]
    const float* __restrict__ bq, const float* __restrict__ bk,
    const float* __restrict__ bv,
    const float2* __restrict__ tab,            // [2048][32] (cos,sin)
    unsigned short* __restrict__ qkv)          // q|k|v f16 [3][B,H,T,64]
{
    __shared__ __align__(16) unsigned short As[2 * 128 * 64];
    __shared__ __align__(16) unsigned short Ws[2 * 128 * 64];

    int bid = blockIdx.x;
    int swz = (bid & 7) * 192 + (bid >> 3);
    int bx = swz % 24, by = swz / 24;
    const int sel = bx >> 3;                   // 0=q 1=k 2=v
    const int jb = bx & 7;
    const int n0 = by * 128;
    const int j0 = jb * 128;

    const unsigned short* W = Wall + (size_t)sel * 1048576;
    const float* bias = (sel == 0) ? bq : (sel == 1) ? bk : bv;
    unsigned short* outp = qkv + (size_t)sel * (BB * HH * TT * HD);

    const int tid = threadIdx.x;
    const int w = tid >> 6, lane = tid & 63;
    const int l15 = lane & 15, g = lane >> 4;
    const int wr = w >> 1, wc = w & 1;
    const int wavebase = tid & ~63;            // wave-uniform

    f32x4 acc[4][4];
#pragma unroll
    for (int mi = 0; mi < 4; mi++)
#pragma unroll
        for (int nj = 0; nj < 4; nj++) acc[mi][nj] = (f32x4){0.f, 0.f, 0.f, 0.f};

#define ISSUE(KS, BUF)                                                        \
    {                                                                         \
        _Pragma("unroll")                                                     \
        for (int it = 0; it < 4; it++) {                                      \
            int ci = it * 256 + tid;                                          \
            int r = ci >> 3;                                                  \
            int p = (ci & 7) ^ (r & 7);                                       \
            int lb = (BUF) * 8192 + (it * 256 + wavebase) * 8;                \
            GLDS(A + (size_t)(n0 + r) * 1024 + (KS) + p * 8, As + lb);        \
            GLDS(W + (size_t)(j0 + r) * 1024 + (KS) + p * 8, Ws + lb);        \
        }                                                                     \
    }

    ISSUE(0, 0)

    for (int ki = 0; ki < 16; ki++) {
        const int cur = ki & 1;
        __syncthreads();                       // drains vmcnt -> buf cur ready
        if (ki + 1 < 16) ISSUE((ki + 1) * 64, cur ^ 1)
        const unsigned short* Ab = As + cur * 8192;
        const unsigned short* Wb = Ws + cur * 8192;

#pragma unroll
        for (int c = 0; c < 2; c++) {
            f16x8 af[4], bf[4];
            const int q0c = c * 4 + (g >> 1);
            const int q1c = q0c + 2;
            const int off = (g & 1) << 2;
#pragma unroll
            for (int mi = 0; mi < 4; mi++) {
                int r = wr * 64 + mi * 16 + l15;
                int sw = r & 7;
                const unsigned short* rp = Ab + r * 64;
                u32x2 x0 = *(const u32x2*)(rp + ((q0c ^ sw) << 3) + off);
                u32x2 x1 = *(const u32x2*)(rp + ((q1c ^ sw) << 3) + off);
                u32x4 uu = {x0.x, x0.y, x1.x, x1.y};
                af[mi] = __builtin_bit_cast(f16x8, uu);
            }
#pragma unroll
            for (int nj = 0; nj < 4; nj++) {
                int r = wc * 64 + nj * 16 + l15;
                int sw = r & 7;
                const unsigned short* rp = Wb + r * 64;
                u32x2 x0 = *(const u32x2*)(rp + ((q0c ^ sw) << 3) + off);
                u32x2 x1 = *(const u32x2*)(rp + ((q1c ^ sw) << 3) + off);
                u32x4 uu = {x0.x, x0.y, x1.x, x1.y};
                bf[nj] = __builtin_bit_cast(f16x8, uu);
            }
#pragma unroll
            for (int mi = 0; mi < 4; mi++)
#pragma unroll
                for (int nj = 0; nj < 4; nj++)
                    acc[mi][nj] = __builtin_amdgcn_mfma_f32_16x16x32_f16(
                        af[mi], bf[nj], acc[mi][nj], 0, 0, 0);
        }
    }
#undef ISSUE

    float bb4[4];
#pragma unroll
    for (int nj = 0; nj < 4; nj++) bb4[nj] = bias[j0 + wc * 64 + nj * 16 + l15];
    const int hh = (j0 >> 6) + wc;             // head 0..15

    if (sel == 2) {
#pragma unroll
        for (int mi = 0; mi < 4; mi++)
#pragma unroll
            for (int r = 0; r < 4; r++) {
                int n = n0 + wr * 64 + mi * 16 + 4 * g + r;
                int b = n >> 11, t = n & (TT - 1);
                size_t rowbase = ((size_t)(b * HH + hh) * TT + t) << 6;
#pragma unroll
                for (int nj = 0; nj < 4; nj++) {
                    int dd = nj * 16 + l15;
                    outp[rowbase + dd] = f2h(acc[mi][nj][r] + bb4[nj]);
                }
            }
    } else {
#pragma unroll
        for (int mi = 0; mi < 4; mi++)
#pragma unroll
            for (int r = 0; r < 4; r++) {
                int n = n0 + wr * 64 + mi * 16 + 4 * g + r;
                int b = n >> 11, t = n & (TT - 1);
                size_t rowbase = ((size_t)(b * HH + hh) * TT + t) << 6;
                const float2* tp = tab + t * 32 + l15;
#pragma unroll
                for (int p = 0; p < 2; p++) {
                    float2 cs = tp[p * 16];
                    float x1 = acc[mi][p][r]     + bb4[p];
                    float x2 = acc[mi][p + 2][r] + bb4[p + 2];
                    int i = p * 16 + l15;
                    outp[rowbase + i]      = f2h(x1 * cs.x - x2 * cs.y);
                    outp[rowbase + i + 32] = f2h(x2 * cs.x + x1 * cs.y);
                }
            }
    }
}

// ---------------------------------------------------------------------------
// MFMA f16 GEMM for O-projection. R11: gload_lds double-buffer (same scheme).
// ---------------------------------------------------------------------------
__global__ __launch_bounds__(256) void gemm_h(
    const unsigned short* __restrict__ A, const unsigned short* __restrict__ W,
    const float* __restrict__ bias, float* __restrict__ outp,
    int N, int K, int J)
{
    __shared__ __align__(16) unsigned short As[2 * 128 * 64];
    __shared__ __align__(16) unsigned short Ws[2 * 128 * 64];

    int total = gridDim.x * gridDim.y;
    int flat = blockIdx.y * gridDim.x + blockIdx.x;
    int swz = (flat & 7) * (total >> 3) + (flat >> 3);
    int bxi = swz % gridDim.x, byi = swz / gridDim.x;

    const int tid = threadIdx.x;
    const int w = tid >> 6, lane = tid & 63;
    const int l15 = lane & 15, g = lane >> 4;
    const int wr = w >> 1, wc = w & 1;
    const int n0 = byi * 128;
    const int j0 = bxi * 128;
    const int wavebase = tid & ~63;

    f32x4 acc[4][4];
#pragma unroll
    for (int mi = 0; mi < 4; mi++)
#pragma unroll
        for (int nj = 0; nj < 4; nj++) acc[mi][nj] = (f32x4){0.f, 0.f, 0.f, 0.f};

#define ISSUE(KS, BUF)                                                        \
    {                                                                         \
        _Pragma("unroll")                                                     \
        for (int it = 0; it < 4; it++) {                                      \
            int ci = it * 256 + tid;                                          \
            int r = ci >> 3;                                                  \
            int p = (ci & 7) ^ (r & 7);                                       \
            int lb = (BUF) * 8192 + (it * 256 + wavebase) * 8;                \
            GLDS(A + (size_t)(n0 + r) * K + (KS) + p * 8, As + lb);           \
            GLDS(W + (size_t)(j0 + r) * K + (KS) + p * 8, Ws + lb);           \
        }                                                                     \
    }

    const int nks = K >> 6;
    ISSUE(0, 0)

    for (int ki = 0; ki < nks; ki++) {
        const int cur = ki & 1;
        __syncthreads();                       // drains vmcnt -> buf cur ready
        if (ki + 1 < nks) ISSUE((ki + 1) * 64, cur ^ 1)
        const unsigned short* Ab = As + cur * 8192;
        const unsigned short* Wb = Ws + cur * 8192;

#pragma unroll
        for (int c = 0; c < 2; c++) {
            f16x8 af[4], bf[4];
            const int q0c = c * 4 + (g >> 1);
            const int q1c = q0c + 2;
            const int off = (g & 1) << 2;
#pragma unroll
            for (int mi = 0; mi < 4; mi++) {
                int r = wr * 64 + mi * 16 + l15;
                int sw = r & 7;
                const unsigned short* rp = Ab + r * 64;
                u32x2 x0 = *(const u32x2*)(rp + ((q0c ^ sw) << 3) + off);
                u32x2 x1 = *(const u32x2*)(rp + ((q1c ^ sw) << 3) + off);
                u32x4 uu = {x0.x, x0.y, x1.x, x1.y};
                af[mi] = __builtin_bit_cast(f16x8, uu);
            }
#pragma unroll
            for (int nj = 0; nj < 4; nj++) {
                int r = wc * 64 + nj * 16 + l15;
                int sw = r & 7;
                const unsigned short* rp = Wb + r * 64;
                u32x2 x0 = *(const u32x2*)(rp + ((q0c ^ sw) << 3) + off);
                u32x2 x1 = *(const u32x2*)(rp + ((q1c ^ sw) << 3) + off);
                u32x4 uu = {x0.x, x0.y, x1.x, x1.y};
                bf[nj] = __builtin_bit_cast(f16x8, uu);
            }
#pragma unroll
            for (int mi = 0; mi < 4; mi++)
#pragma unroll
                for (int nj = 0; nj < 4; nj++)
                    acc[mi][nj] = __builtin_amdgcn_mfma_f32_16x16x32_f16(
                        af[mi], bf[nj], acc[mi][nj], 0, 0, 0);
        }
    }
#undef ISSUE

#pragma unroll
    for (int nj = 0; nj < 4; nj++) {
        int j = j0 + wc * 64 + nj * 16 + l15;
        float bb = bias[j];
#pragma unroll
        for (int mi = 0; mi < 4; mi++)
#pragma unroll
            for (int r = 0; r < 4; r++) {
                int n = n0 + wr * 64 + mi * 16 + 4 * g + r;
                outp[(size_t)n * J + j] = acc[mi][nj][r] + bb;
            }
    }
}

// ---------------------------------------------------------------------------
// MFMA flash attention (f16) — VERIFIED R10 8-wave QBLK=128, unchanged.
// ---------------------------------------------------------------------------
__device__ __forceinline__ u32x2 ds_tr16(const unsigned short* p) {
    u32x2 r;
    asm volatile("ds_read_b64_tr_b16 %0, %1"
                 : "=v"(r)
                 : "v"((unsigned int)(unsigned long long)p));
    return r;
}

__global__ __launch_bounds__(512, 4) void attn_mfma(
    const unsigned short* __restrict__ q,
    const unsigned short* __restrict__ k,
    const unsigned short* __restrict__ v,
    unsigned short* __restrict__ aout)
{
    __shared__ __align__(16) unsigned short Ks[64 * 64];   // swizzled [key][dim]
    __shared__ __align__(16) unsigned short Vs[4 * 1056];  // [db][key][16]

    const int h = blockIdx.y, b = blockIdx.z;
    const int tid = threadIdx.x;
    const int w = tid >> 6;              // wave 0..7
    const int wd = w & 3;
    const int wt = w >> 2;               // which 64-row half of the 128 block
    const int lane = tid & 63;
    const int l15 = lane & 15, g = lane >> 4;
    const int bh = b * HH + h;
    const size_t base = (size_t)bh * TT * 64;
    const unsigned short* Qp = q + base;
    const unsigned short* Kp = k + base;
    const unsigned short* Vp = v + base;

    const float SC = 0.18033688011112042f;   // log2(e)/8

    u32x4 kreg;
    u32x2 vreg[2];
#define LOADKV(KB)                                                             \
    {                                                                          \
        {                                                                      \
            int key = tid >> 3, pr = tid & 7;                                  \
            kreg = *(const u32x4*)(Kp + (size_t)((KB) + key) * 64 + pr * 8);   \
        }                                                                      \
        _Pragma("unroll")                                                      \
        for (int it = 0; it < 2; it++) {                                       \
            int vi = tid + it * 512;                                           \
            int key = vi >> 4, c4 = vi & 15;                                   \
            vreg[it] = *(const u32x2*)(Vp + (size_t)((KB) + key) * 64 + c4 * 4);\
        }                                                                      \
    }

    for (int ph = 0; ph < 2; ph++) {
        const int qs = ph ? (15 - (int)blockIdx.x) : (int)blockIdx.x;
        const int q0 = qs * 128;
        const int dtile = 2 * qs + wt;

        f16x8 qf[2];
        {
            const unsigned short* Qr = Qp + (size_t)(q0 + w * 16 + l15) * 64;
#pragma unroll
            for (int c = 0; c < 2; c++) {
                u32x2 a0 = *(const u32x2*)(Qr + 32 * c + 4 * g);
                u32x2 a1 = *(const u32x2*)(Qr + 32 * c + 16 + 4 * g);
                u32x4 uu = {a0.x, a0.y, a1.x, a1.y};
                qf[c] = __builtin_bit_cast(f16x8, uu);
            }
        }

        float mrow = -1e30f, lrow = 0.f;
        f32x4 accO[4];
#pragma unroll
        for (int nb = 0; nb < 4; nb++) accO[nb] = (f32x4){0.f, 0.f, 0.f, 0.f};

        const int ntiles = 2 * qs + 2;
        LOADKV(0)

        for (int kt = 0; kt < ntiles; kt++) {
            const bool active = (kt <= dtile);
            const bool diag = (kt == dtile);
            __syncthreads();
            {
                int key = tid >> 3, pr = tid & 7;
                *(u32x4*)(Ks + key * 64 + ((pr ^ (key & 7)) << 3)) = kreg;
            }
#pragma unroll
            for (int it = 0; it < 2; it++) {
                int vi = tid + it * 512;
                int key = vi >> 4, c4 = vi & 15;
                *(u32x2*)(Vs + (c4 >> 2) * 1056 + key * 16 + (c4 & 3) * 4) = vreg[it];
            }
            __syncthreads();
            if (kt + 1 < ntiles) LOADKV((kt + 1) * 64)

            if (active) {
                const int nkb = diag ? (wd + 1) : 4;
                f32x4 accS[4];
#pragma unroll
                for (int kb = 0; kb < 4; kb++) accS[kb] = (f32x4){0.f, 0.f, 0.f, 0.f};
                __builtin_amdgcn_s_setprio(1);
#pragma unroll
                for (int kb = 0; kb < 4; kb++) {
                    if (kb < nkb) {
                        int key = kb * 16 + l15;
                        int sw = key & 7;
#pragma unroll
                        for (int c = 0; c < 2; c++) {
                            int c8a = 8 * c + g, c8b = 8 * c + 4 + g;
                            u32x2 x0 = *(const u32x2*)(Ks + key * 64 +
                                           (((c8a >> 1) ^ sw) << 3) + ((c8a & 1) << 2));
                            u32x2 x1 = *(const u32x2*)(Ks + key * 64 +
                                           (((c8b >> 1) ^ sw) << 3) + ((c8b & 1) << 2));
                            u32x4 uu = {x0.x, x0.y, x1.x, x1.y};
                            accS[kb] = __builtin_amdgcn_mfma_f32_16x16x32_f16(
                                __builtin_bit_cast(f16x8, uu), qf[c], accS[kb], 0, 0, 0);
                        }
                    }
                }
                __builtin_amdgcn_s_setprio(0);

                float sloc[16];
                float tmax = -1e30f;
                if (diag) {
#pragma unroll
                    for (int kb = 0; kb < 4; kb++)
#pragma unroll
                        for (int r = 0; r < 4; r++) {
                            float s = accS[kb][r];
                            bool valid = (kb * 16 + 4 * g + r <= wd * 16 + l15);
                            s = valid ? s : -1e30f;
                            sloc[kb * 4 + r] = s;
                            tmax = fmaxf(tmax, s);
                        }
                } else {
#pragma unroll
                    for (int kb = 0; kb < 4; kb++)
#pragma unroll
                        for (int r = 0; r < 4; r++) {
                            float s = accS[kb][r];
                            sloc[kb * 4 + r] = s;
                            tmax = fmaxf(tmax, s);
                        }
                }
                tmax = fmaxf(tmax, __shfl_xor(tmax, 16));
                tmax = fmaxf(tmax, __shfl_xor(tmax, 32));

                if (!__all(tmax - mrow <= 61.0f)) {     // 61*SC = 11 log2-units
                    float mnew = fmaxf(mrow, tmax);
                    float sf = exp2f((mrow - mnew) * SC);
                    mrow = mnew;
                    lrow *= sf;
                    float sfr[4];
#pragma unroll
                    for (int r = 0; r < 4; r++) sfr[r] = __shfl(sf, 4 * g + r);
#pragma unroll
                    for (int nb = 0; nb < 4; nb++)
#pragma unroll
                        for (int r = 0; r < 4; r++) accO[nb][r] *= sfr[r];
                }

                const float nmsc = -mrow * SC;
                unsigned int pw[8];
                float psum = 0.f;
#pragma unroll
                for (int i = 0; i < 8; i++) {
                    float p0 = exp2f(fmaf(sloc[2 * i],     SC, nmsc));
                    float p1 = exp2f(fmaf(sloc[2 * i + 1], SC, nmsc));
                    pw[i] = pkrtz(p0, p1);
                    psum += p0 + p1;
                }
                psum += __shfl_xor(psum, 16);
                psum += __shfl_xor(psum, 32);
                lrow += psum;

                const int nkc = (diag && wd < 2) ? 1 : 2;
#pragma unroll
                for (int kc = 0; kc < 2; kc++)
                    if (kc < nkc) {
                        u32x2 vfr[4][2];
#pragma unroll
                        for (int nb = 0; nb < 4; nb++)
#pragma unroll
                            for (int t2 = 0; t2 < 2; t2++)
                                vfr[nb][t2] = ds_tr16(
                                    Vs + nb * 1056 + (kc * 32 + 16 * t2) * 16 + 4 * lane);
                        asm volatile("s_waitcnt lgkmcnt(0)" ::: "memory");
                        __builtin_amdgcn_sched_barrier(0);
                        u32x4 pu = {pw[4 * kc + 0], pw[4 * kc + 1], pw[4 * kc + 2], pw[4 * kc + 3]};
                        f16x8 pf = __builtin_bit_cast(f16x8, pu);
                        __builtin_amdgcn_s_setprio(1);
#pragma unroll
                        for (int nb = 0; nb < 4; nb++) {
                            u32x4 vu = {vfr[nb][0].x, vfr[nb][0].y,
                                        vfr[nb][1].x, vfr[nb][1].y};
                            accO[nb] = __builtin_amdgcn_mfma_f32_16x16x32_f16(
                                pf, __builtin_bit_cast(f16x8, vu), accO[nb], 0, 0, 0);
                        }
                        __builtin_amdgcn_s_setprio(0);
                    }
            }
        }

        float linv = 1.0f / lrow;
        float sfr[4];
#pragma unroll
        for (int r = 0; r < 4; r++) sfr[r] = __shfl(linv, 4 * g + r);
#pragma unroll
        for (int r = 0; r < 4; r++) {
            int qr = q0 + w * 16 + 4 * g + r;
            unsigned short* orow = aout + (size_t)(b * TT + qr) * DD + h * 64;
#pragma unroll
            for (int nb = 0; nb < 4; nb++)
                orow[nb * 16 + l15] = f2h(accO[nb][r] * sfr[r]);
        }
    }
#undef LOADKV
}

// ---------------------------------------------------------------------------
extern "C" void kernel_launch(void* const* d_in, const int* in_sizes, int n_in,
                              void* d_out, int out_size, void* d_ws, size_t ws_size,
                              hipStream_t stream)
{
    const float* x  = (const float*)d_in[0];
    const float* Wq = (const float*)d_in[1];
    const float* bq = (const float*)d_in[2];
    const float* Wk = (const float*)d_in[3];
    const float* bk = (const float*)d_in[4];
    const float* Wv = (const float*)d_in[5];
    const float* bv = (const float*)d_in[6];
    const float* Wo = (const float*)d_in[7];
    const float* bo = (const float*)d_in[8];
    float* out = (float*)d_out;                     // FLOAT32 output [B,T,D]

    const size_t NE = (size_t)BB * HH * TT * HD;    // 8388608 elements
    // ws: q|k|v f16 contiguous. Direct mode (ws >= 67.1 MB): att f16 at
    // ws[3NE..4NE); Wo_h in dead q region; gemm_h -> d_out (no memcpy).
    // Fallback: att in d_out scratch, Wo_h in d_out after tab, gemm_h -> ws
    // res + memcpy (verified R6 structure).
    unsigned short* qkv  = (unsigned short*)d_ws;
    unsigned short* qb   = qkv;
    unsigned short* kbuf = qkv + NE;
    unsigned short* vbuf = qkv + 2 * NE;
    float* res = (float*)d_ws;                      // overlays dead q+k (fallback)

    // d_out scratch (all dead before the final result lands):
    //  elements [0 .. 8388608)         x_h f16 (fallback: att_h overlays)
    //  elements [8388608 .. 11534336)  wq|wk|wv f16
    //  elements [11534336 .. 11796480) rope table float2 [2048][32]
    //  elements [11796480 .. 12845056) Wo_h f16 (FALLBACK only)
    unsigned short* ds  = (unsigned short*)d_out;
    unsigned short* xh  = ds;
    unsigned short* wh  = ds + 8388608;
    float2* tab = (float2*)(ds + 11534336);

    const bool direct = ws_size >= (size_t)8 * NE;  // bytes: 4 f16 regions
    unsigned short* att = direct ? (qkv + 3 * NE) : ds;
    unsigned short* woh = direct ? (unsigned short*)d_ws : (ds + 11796480);
    float* resout = direct ? out : res;

    const int N = BB * TT;                          // 8192 tokens
    dim3 blk(256);

    // 1) convert x + Wq|Wk|Wv to f16, build rope table (single launch)
    conv_all<<<11520, blk, 0, stream>>>(
        (const float4*)x, (const float4*)Wq, (const float4*)Wk,
        (const float4*)Wv, (ushort4*)xh, (ushort4*)wh, tab);

    // 2) fused QKV projection + table RoPE (single launch, XCD-swizzled)
    gemm_qkv<<<1536, blk, 0, stream>>>(xh, wh, bq, bk, bv, tab, qkv);

    // 3) flash attention (8-wave QBLK=128) -> att f16
    attn_mfma<<<dim3(8, HH, BB), dim3(512), 0, stream>>>(qb, kbuf, vbuf, att);

    // 4) convert Wo AFTER attn into a region gemm_h never writes
    conv_wo<<<1024, blk, 0, stream>>>((const float4*)Wo, (ushort4*)woh);

    // 5) O-projection -> f32 (direct: into d_out; fallback: ws res)
    gemm_h<<<dim3(DD / 128, N / 128), blk, 0, stream>>>(att, woh, bo, resout, N, DD, DD);

    // 6) fallback copy
    if (!direct)
        hipMemcpyAsync(out, res, (size_t)N * DD * sizeof(float),
                       hipMemcpyDeviceToDevice, stream);
}

// Round 12
// 276.381 us; speedup vs baseline: 1.9482x; 1.0272x over previous
//
#include <hip/hip_runtime.h>

// Problem constants: B=4, T=2048, D=1024, H=16, HD=64
// Math (certified r6): torch convention x@W.T+b, rotate-half RoPE pos=t+1,
// causal softmax(QK^T/8)V, O-proj. Output f32 [B,T,D].
// R12: counted-vmcnt GEMM pipeline (T4). Same 2-buffer gload_lds structure
// as R11, but: s_waitcnt vmcnt(8) + raw s_barrier (tile ki's 8 loads
// retired, tile ki+1's 8 stay IN FLIGHT across the barrier) + second raw
// s_barrier after compute before refilling the buffer. Tail uses vmcnt(0).
// attn = verified R10; plumbing = verified R9.
#define BB 4
#define TT 2048
#define DD 1024
#define HH 16
#define HD 64

typedef __attribute__((ext_vector_type(8))) _Float16 f16x8;
typedef __attribute__((ext_vector_type(4))) float f32x4;
typedef __attribute__((ext_vector_type(2))) unsigned int u32x2;
typedef __attribute__((ext_vector_type(4))) unsigned int u32x4;

__device__ __forceinline__ float h2f(unsigned short u) {
    return (float)__builtin_bit_cast(_Float16, u);
}
__device__ __forceinline__ unsigned short f2h(float f) {
    return __builtin_bit_cast(unsigned short, (_Float16)f);
}
__device__ __forceinline__ unsigned int pkrtz(float a, float b) {
    return __builtin_bit_cast(unsigned int, __builtin_amdgcn_cvt_pkrtz(a, b));
}

// ---------------------------------------------------------------------------
// Fused f32 -> f16 convert: x + Wq|Wk|Wv + RoPE (cos,sin) table.
// ---------------------------------------------------------------------------
__global__ __launch_bounds__(256) void conv_all(
    const float4* __restrict__ x,
    const float4* __restrict__ Wq, const float4* __restrict__ Wk,
    const float4* __restrict__ Wv,
    ushort4* __restrict__ xh, ushort4* __restrict__ wh,
    float2* __restrict__ tab)
{
    int vi = blockIdx.x * 256 + threadIdx.x;
    if (vi < 2097152) {
        float4 v = x[vi];
        xh[vi] = (ushort4){ f2h(v.x), f2h(v.y), f2h(v.z), f2h(v.w) };
    } else if (vi < 2883584) {
        int u = vi - 2097152;               // [0, 786432)
        int w = u >> 18;                    // 0..2 (uniform per block)
        const float4* src = (w == 0) ? Wq : (w == 1) ? Wk : Wv;
        float4 v = src[u & 262143];
        wh[u] = (ushort4){ f2h(v.x), f2h(v.y), f2h(v.z), f2h(v.w) };
    } else {
        int u = vi - 2883584;               // [0, 65536): (t, i)
        int t = u >> 5, i = u & 31;
        float ang = (float)(t + 1) *
                    exp2f(-(float)i * (13.287712379549449f / 32.0f));
        tab[u] = (float2){ cosf(ang), sinf(ang) };
    }
}

// Wo f32 -> f16 (launched AFTER attn; dst never aliased with gemm_h writes).
__global__ __launch_bounds__(256) void conv_wo(
    const float4* __restrict__ Wo, ushort4* __restrict__ dst)
{
    int i = blockIdx.x * 256 + threadIdx.x;   // 262144 total
    float4 v = Wo[i];
    dst[i] = (ushort4){ f2h(v.x), f2h(v.y), f2h(v.z), f2h(v.w) };
}

// ---------------------------------------------------------------------------
// Staging: global_load_lds dwordx4, linear LDS dest (wave-uniform base +
// lane*16B), source chunk pre-swizzled p = pp ^ (r&7) (involution).
// ---------------------------------------------------------------------------
#define GLDS(gp, lp)                                                          \
    __builtin_amdgcn_global_load_lds(                                         \
        (const __attribute__((address_space(1))) unsigned int*)(gp),          \
        (__attribute__((address_space(3))) unsigned int*)(lp), 16, 0, 0)

// ---------------------------------------------------------------------------
// Fused QKV MFMA GEMM + table RoPE epilogue. R12: counted-vmcnt pipeline.
// ---------------------------------------------------------------------------
__global__ __launch_bounds__(256) void gemm_qkv(
    const unsigned short* __restrict__ A,      // x_h [8192][1024]
    const unsigned short* __restrict__ Wall,   // wq|wk|wv f16 [3][1024][1024]
    const float* __restrict__ bq, const float* __restrict__ bk,
    const float* __restrict__ bv,
    const float2* __restrict__ tab,            // [2048][32] (cos,sin)
    unsigned short* __restrict__ qkv)          // q|k|v f16 [3][B,H,T,64]
{
    __shared__ __align__(16) unsigned short As[2 * 128 * 64];
    __shared__ __align__(16) unsigned short Ws[2 * 128 * 64];

    int bid = blockIdx.x;
    int swz = (bid & 7) * 192 + (bid >> 3);
    int bx = swz % 24, by = swz / 24;
    const int sel = bx >> 3;                   // 0=q 1=k 2=v
    const int jb = bx & 7;
    const int n0 = by * 128;
    const int j0 = jb * 128;

    const unsigned short* W = Wall + (size_t)sel * 1048576;
    const float* bias = (sel == 0) ? bq : (sel == 1) ? bk : bv;
    unsigned short* outp = qkv + (size_t)sel * (BB * HH * TT * HD);

    const int tid = threadIdx.x;
    const int w = tid >> 6, lane = tid & 63;
    const int l15 = lane & 15, g = lane >> 4;
    const int wr = w >> 1, wc = w & 1;
    const int wavebase = tid & ~63;            // wave-uniform

    f32x4 acc[4][4];
#pragma unroll
    for (int mi = 0; mi < 4; mi++)
#pragma unroll
        for (int nj = 0; nj < 4; nj++) acc[mi][nj] = (f32x4){0.f, 0.f, 0.f, 0.f};

#define ISSUE(KS, BUF)                                                        \
    {                                                                         \
        _Pragma("unroll")                                                     \
        for (int it = 0; it < 4; it++) {                                      \
            int ci = it * 256 + tid;                                          \
            int r = ci >> 3;                                                  \
            int p = (ci & 7) ^ (r & 7);                                       \
            int lb = (BUF) * 8192 + (it * 256 + wavebase) * 8;                \
            GLDS(A + (size_t)(n0 + r) * 1024 + (KS) + p * 8, As + lb);        \
            GLDS(W + (size_t)(j0 + r) * 1024 + (KS) + p * 8, Ws + lb);        \
        }                                                                     \
    }

    ISSUE(0, 0)
    ISSUE(64, 1)                               // 16 loads in flight

    for (int ki = 0; ki < 16; ki++) {
        const int cur = ki & 1;
        // wait for tile ki's 8 loads; tile ki+1's 8 stay in flight
        if (ki < 15) asm volatile("s_waitcnt vmcnt(8)" ::: "memory");
        else         asm volatile("s_waitcnt vmcnt(0)" ::: "memory");
        __builtin_amdgcn_s_barrier();          // all waves' tile-ki loads landed
        const unsigned short* Ab = As + cur * 8192;
        const unsigned short* Wb = Ws + cur * 8192;

#pragma unroll
        for (int c = 0; c < 2; c++) {
            f16x8 af[4], bf[4];
            const int q0c = c * 4 + (g >> 1);
            const int q1c = q0c + 2;
            const int off = (g & 1) << 2;
#pragma unroll
            for (int mi = 0; mi < 4; mi++) {
                int r = wr * 64 + mi * 16 + l15;
                int sw = r & 7;
                const unsigned short* rp = Ab + r * 64;
                u32x2 x0 = *(const u32x2*)(rp + ((q0c ^ sw) << 3) + off);
                u32x2 x1 = *(const u32x2*)(rp + ((q1c ^ sw) << 3) + off);
                u32x4 uu = {x0.x, x0.y, x1.x, x1.y};
                af[mi] = __builtin_bit_cast(f16x8, uu);
            }
#pragma unroll
            for (int nj = 0; nj < 4; nj++) {
                int r = wc * 64 + nj * 16 + l15;
                int sw = r & 7;
                const unsigned short* rp = Wb + r * 64;
                u32x2 x0 = *(const u32x2*)(rp + ((q0c ^ sw) << 3) + off);
                u32x2 x1 = *(const u32x2*)(rp + ((q1c ^ sw) << 3) + off);
                u32x4 uu = {x0.x, x0.y, x1.x, x1.y};
                bf[nj] = __builtin_bit_cast(f16x8, uu);
            }
#pragma unroll
            for (int mi = 0; mi < 4; mi++)
#pragma unroll
                for (int nj = 0; nj < 4; nj++)
                    acc[mi][nj] = __builtin_amdgcn_mfma_f32_16x16x32_f16(
                        af[mi], bf[nj], acc[mi][nj], 0, 0, 0);
        }

        __builtin_amdgcn_s_barrier();          // all waves done reading cur
        if (ki + 2 < 16) ISSUE((ki + 2) * 64, cur)
    }
#undef ISSUE

    float bb4[4];
#pragma unroll
    for (int nj = 0; nj < 4; nj++) bb4[nj] = bias[j0 + wc * 64 + nj * 16 + l15];
    const int hh = (j0 >> 6) + wc;             // head 0..15

    if (sel == 2) {
#pragma unroll
        for (int mi = 0; mi < 4; mi++)
#pragma unroll
            for (int r = 0; r < 4; r++) {
                int n = n0 + wr * 64 + mi * 16 + 4 * g + r;
                int b = n >> 11, t = n & (TT - 1);
                size_t rowbase = ((size_t)(b * HH + hh) * TT + t) << 6;
#pragma unroll
                for (int nj = 0; nj < 4; nj++) {
                    int dd = nj * 16 + l15;
                    outp[rowbase + dd] = f2h(acc[mi][nj][r] + bb4[nj]);
                }
            }
    } else {
#pragma unroll
        for (int mi = 0; mi < 4; mi++)
#pragma unroll
            for (int r = 0; r < 4; r++) {
                int n = n0 + wr * 64 + mi * 16 + 4 * g + r;
                int b = n >> 11, t = n & (TT - 1);
                size_t rowbase = ((size_t)(b * HH + hh) * TT + t) << 6;
                const float2* tp = tab + t * 32 + l15;
#pragma unroll
                for (int p = 0; p < 2; p++) {
                    float2 cs = tp[p * 16];
                    float x1 = acc[mi][p][r]     + bb4[p];
                    float x2 = acc[mi][p + 2][r] + bb4[p + 2];
                    int i = p * 16 + l15;
                    outp[rowbase + i]      = f2h(x1 * cs.x - x2 * cs.y);
                    outp[rowbase + i + 32] = f2h(x2 * cs.x + x1 * cs.y);
                }
            }
    }
}

// ---------------------------------------------------------------------------
// MFMA f16 GEMM for O-projection. R12: counted-vmcnt pipeline (same scheme).
// ---------------------------------------------------------------------------
__global__ __launch_bounds__(256) void gemm_h(
    const unsigned short* __restrict__ A, const unsigned short* __restrict__ W,
    const float* __restrict__ bias, float* __restrict__ outp,
    int N, int K, int J)
{
    __shared__ __align__(16) unsigned short As[2 * 128 * 64];
    __shared__ __align__(16) unsigned short Ws[2 * 128 * 64];

    int total = gridDim.x * gridDim.y;
    int flat = blockIdx.y * gridDim.x + blockIdx.x;
    int swz = (flat & 7) * (total >> 3) + (flat >> 3);
    int bxi = swz % gridDim.x, byi = swz / gridDim.x;

    const int tid = threadIdx.x;
    const int w = tid >> 6, lane = tid & 63;
    const int l15 = lane & 15, g = lane >> 4;
    const int wr = w >> 1, wc = w & 1;
    const int n0 = byi * 128;
    const int j0 = bxi * 128;
    const int wavebase = tid & ~63;

    f32x4 acc[4][4];
#pragma unroll
    for (int mi = 0; mi < 4; mi++)
#pragma unroll
        for (int nj = 0; nj < 4; nj++) acc[mi][nj] = (f32x4){0.f, 0.f, 0.f, 0.f};

#define ISSUE(KS, BUF)                                                        \
    {                                                                         \
        _Pragma("unroll")                                                     \
        for (int it = 0; it < 4; it++) {                                      \
            int ci = it * 256 + tid;                                          \
            int r = ci >> 3;                                                  \
            int p = (ci & 7) ^ (r & 7);                                       \
            int lb = (BUF) * 8192 + (it * 256 + wavebase) * 8;                \
            GLDS(A + (size_t)(n0 + r) * K + (KS) + p * 8, As + lb);           \
            GLDS(W + (size_t)(j0 + r) * K + (KS) + p * 8, Ws + lb);           \
        }                                                                     \
    }

    const int nks = K >> 6;
    ISSUE(0, 0)
    if (nks > 1) ISSUE(64, 1)

    for (int ki = 0; ki < nks; ki++) {
        const int cur = ki & 1;
        if (ki < nks - 1) asm volatile("s_waitcnt vmcnt(8)" ::: "memory");
        else              asm volatile("s_waitcnt vmcnt(0)" ::: "memory");
        __builtin_amdgcn_s_barrier();
        const unsigned short* Ab = As + cur * 8192;
        const unsigned short* Wb = Ws + cur * 8192;

#pragma unroll
        for (int c = 0; c < 2; c++) {
            f16x8 af[4], bf[4];
            const int q0c = c * 4 + (g >> 1);
            const int q1c = q0c + 2;
            const int off = (g & 1) << 2;
#pragma unroll
            for (int mi = 0; mi < 4; mi++) {
                int r = wr * 64 + mi * 16 + l15;
                int sw = r & 7;
                const unsigned short* rp = Ab + r * 64;
                u32x2 x0 = *(const u32x2*)(rp + ((q0c ^ sw) << 3) + off);
                u32x2 x1 = *(const u32x2*)(rp + ((q1c ^ sw) << 3) + off);
                u32x4 uu = {x0.x, x0.y, x1.x, x1.y};
                af[mi] = __builtin_bit_cast(f16x8, uu);
            }
#pragma unroll
            for (int nj = 0; nj < 4; nj++) {
                int r = wc * 64 + nj * 16 + l15;
                int sw = r & 7;
                const unsigned short* rp = Wb + r * 64;
                u32x2 x0 = *(const u32x2*)(rp + ((q0c ^ sw) << 3) + off);
                u32x2 x1 = *(const u32x2*)(rp + ((q1c ^ sw) << 3) + off);
                u32x4 uu = {x0.x, x0.y, x1.x, x1.y};
                bf[nj] = __builtin_bit_cast(f16x8, uu);
            }
#pragma unroll
            for (int mi = 0; mi < 4; mi++)
#pragma unroll
                for (int nj = 0; nj < 4; nj++)
                    acc[mi][nj] = __builtin_amdgcn_mfma_f32_16x16x32_f16(
                        af[mi], bf[nj], acc[mi][nj], 0, 0, 0);
        }

        __builtin_amdgcn_s_barrier();
        if (ki + 2 < nks) ISSUE((ki + 2) * 64, cur)
    }
#undef ISSUE

#pragma unroll
    for (int nj = 0; nj < 4; nj++) {
        int j = j0 + wc * 64 + nj * 16 + l15;
        float bb = bias[j];
#pragma unroll
        for (int mi = 0; mi < 4; mi++)
#pragma unroll
            for (int r = 0; r < 4; r++) {
                int n = n0 + wr * 64 + mi * 16 + 4 * g + r;
                outp[(size_t)n * J + j] = acc[mi][nj][r] + bb;
            }
    }
}

// ---------------------------------------------------------------------------
// MFMA flash attention (f16) — VERIFIED R10 8-wave QBLK=128, unchanged.
// ---------------------------------------------------------------------------
__device__ __forceinline__ u32x2 ds_tr16(const unsigned short* p) {
    u32x2 r;
    asm volatile("ds_read_b64_tr_b16 %0, %1"
                 : "=v"(r)
                 : "v"((unsigned int)(unsigned long long)p));
    return r;
}

__global__ __launch_bounds__(512, 4) void attn_mfma(
    const unsigned short* __restrict__ q,
    const unsigned short* __restrict__ k,
    const unsigned short* __restrict__ v,
    unsigned short* __restrict__ aout)
{
    __shared__ __align__(16) unsigned short Ks[64 * 64];   // swizzled [key][dim]
    __shared__ __align__(16) unsigned short Vs[4 * 1056];  // [db][key][16]

    const int h = blockIdx.y, b = blockIdx.z;
    const int tid = threadIdx.x;
    const int w = tid >> 6;              // wave 0..7
    const int wd = w & 3;
    const int wt = w >> 2;               // which 64-row half of the 128 block
    const int lane = tid & 63;
    const int l15 = lane & 15, g = lane >> 4;
    const int bh = b * HH + h;
    const size_t base = (size_t)bh * TT * 64;
    const unsigned short* Qp = q + base;
    const unsigned short* Kp = k + base;
    const unsigned short* Vp = v + base;

    const float SC = 0.18033688011112042f;   // log2(e)/8

    u32x4 kreg;
    u32x2 vreg[2];
#define LOADKV(KB)                                                             \
    {                                                                          \
        {                                                                      \
            int key = tid >> 3, pr = tid & 7;                                  \
            kreg = *(const u32x4*)(Kp + (size_t)((KB) + key) * 64 + pr * 8);   \
        }                                                                      \
        _Pragma("unroll")                                                      \
        for (int it = 0; it < 2; it++) {                                       \
            int vi = tid + it * 512;                                           \
            int key = vi >> 4, c4 = vi & 15;                                   \
            vreg[it] = *(const u32x2*)(Vp + (size_t)((KB) + key) * 64 + c4 * 4);\
        }                                                                      \
    }

    for (int ph = 0; ph < 2; ph++) {
        const int qs = ph ? (15 - (int)blockIdx.x) : (int)blockIdx.x;
        const int q0 = qs * 128;
        const int dtile = 2 * qs + wt;

        f16x8 qf[2];
        {
            const unsigned short* Qr = Qp + (size_t)(q0 + w * 16 + l15) * 64;
#pragma unroll
            for (int c = 0; c < 2; c++) {
                u32x2 a0 = *(const u32x2*)(Qr + 32 * c + 4 * g);
                u32x2 a1 = *(const u32x2*)(Qr + 32 * c + 16 + 4 * g);
                u32x4 uu = {a0.x, a0.y, a1.x, a1.y};
                qf[c] = __builtin_bit_cast(f16x8, uu);
            }
        }

        float mrow = -1e30f, lrow = 0.f;
        f32x4 accO[4];
#pragma unroll
        for (int nb = 0; nb < 4; nb++) accO[nb] = (f32x4){0.f, 0.f, 0.f, 0.f};

        const int ntiles = 2 * qs + 2;
        LOADKV(0)

        for (int kt = 0; kt < ntiles; kt++) {
            const bool active = (kt <= dtile);
            const bool diag = (kt == dtile);
            __syncthreads();
            {
                int key = tid >> 3, pr = tid & 7;
                *(u32x4*)(Ks + key * 64 + ((pr ^ (key & 7)) << 3)) = kreg;
            }
#pragma unroll
            for (int it = 0; it < 2; it++) {
                int vi = tid + it * 512;
                int key = vi >> 4, c4 = vi & 15;
                *(u32x2*)(Vs + (c4 >> 2) * 1056 + key * 16 + (c4 & 3) * 4) = vreg[it];
            }
            __syncthreads();
            if (kt + 1 < ntiles) LOADKV((kt + 1) * 64)

            if (active) {
                const int nkb = diag ? (wd + 1) : 4;
                f32x4 accS[4];
#pragma unroll
                for (int kb = 0; kb < 4; kb++) accS[kb] = (f32x4){0.f, 0.f, 0.f, 0.f};
                __builtin_amdgcn_s_setprio(1);
#pragma unroll
                for (int kb = 0; kb < 4; kb++) {
                    if (kb < nkb) {
                        int key = kb * 16 + l15;
                        int sw = key & 7;
#pragma unroll
                        for (int c = 0; c < 2; c++) {
                            int c8a = 8 * c + g, c8b = 8 * c + 4 + g;
                            u32x2 x0 = *(const u32x2*)(Ks + key * 64 +
                                           (((c8a >> 1) ^ sw) << 3) + ((c8a & 1) << 2));
                            u32x2 x1 = *(const u32x2*)(Ks + key * 64 +
                                           (((c8b >> 1) ^ sw) << 3) + ((c8b & 1) << 2));
                            u32x4 uu = {x0.x, x0.y, x1.x, x1.y};
                            accS[kb] = __builtin_amdgcn_mfma_f32_16x16x32_f16(
                                __builtin_bit_cast(f16x8, uu), qf[c], accS[kb], 0, 0, 0);
                        }
                    }
                }
                __builtin_amdgcn_s_setprio(0);

                float sloc[16];
                float tmax = -1e30f;
                if (diag) {
#pragma unroll
                    for (int kb = 0; kb < 4; kb++)
#pragma unroll
                        for (int r = 0; r < 4; r++) {
                            float s = accS[kb][r];
                            bool valid = (kb * 16 + 4 * g + r <= wd * 16 + l15);
                            s = valid ? s : -1e30f;
                            sloc[kb * 4 + r] = s;
                            tmax = fmaxf(tmax, s);
                        }
                } else {
#pragma unroll
                    for (int kb = 0; kb < 4; kb++)
#pragma unroll
                        for (int r = 0; r < 4; r++) {
                            float s = accS[kb][r];
                            sloc[kb * 4 + r] = s;
                            tmax = fmaxf(tmax, s);
                        }
                }
                tmax = fmaxf(tmax, __shfl_xor(tmax, 16));
                tmax = fmaxf(tmax, __shfl_xor(tmax, 32));

                if (!__all(tmax - mrow <= 61.0f)) {     // 61*SC = 11 log2-units
                    float mnew = fmaxf(mrow, tmax);
                    float sf = exp2f((mrow - mnew) * SC);
                    mrow = mnew;
                    lrow *= sf;
                    float sfr[4];
#pragma unroll
                    for (int r = 0; r < 4; r++) sfr[r] = __shfl(sf, 4 * g + r);
#pragma unroll
                    for (int nb = 0; nb < 4; nb++)
#pragma unroll
                        for (int r = 0; r < 4; r++) accO[nb][r] *= sfr[r];
                }

                const float nmsc = -mrow * SC;
                unsigned int pw[8];
                float psum = 0.f;
#pragma unroll
                for (int i = 0; i < 8; i++) {
                    float p0 = exp2f(fmaf(sloc[2 * i],     SC, nmsc));
                    float p1 = exp2f(fmaf(sloc[2 * i + 1], SC, nmsc));
                    pw[i] = pkrtz(p0, p1);
                    psum += p0 + p1;
                }
                psum += __shfl_xor(psum, 16);
                psum += __shfl_xor(psum, 32);
                lrow += psum;

                const int nkc = (diag && wd < 2) ? 1 : 2;
#pragma unroll
                for (int kc = 0; kc < 2; kc++)
                    if (kc < nkc) {
                        u32x2 vfr[4][2];
#pragma unroll
                        for (int nb = 0; nb < 4; nb++)
#pragma unroll
                            for (int t2 = 0; t2 < 2; t2++)
                                vfr[nb][t2] = ds_tr16(
                                    Vs + nb * 1056 + (kc * 32 + 16 * t2) * 16 + 4 * lane);
                        asm volatile("s_waitcnt lgkmcnt(0)" ::: "memory");
                        __builtin_amdgcn_sched_barrier(0);
                        u32x4 pu = {pw[4 * kc + 0], pw[4 * kc + 1], pw[4 * kc + 2], pw[4 * kc + 3]};
                        f16x8 pf = __builtin_bit_cast(f16x8, pu);
                        __builtin_amdgcn_s_setprio(1);
#pragma unroll
                        for (int nb = 0; nb < 4; nb++) {
                            u32x4 vu = {vfr[nb][0].x, vfr[nb][0].y,
                                        vfr[nb][1].x, vfr[nb][1].y};
                            accO[nb] = __builtin_amdgcn_mfma_f32_16x16x32_f16(
                                pf, __builtin_bit_cast(f16x8, vu), accO[nb], 0, 0, 0);
                        }
                        __builtin_amdgcn_s_setprio(0);
                    }
            }
        }

        float linv = 1.0f / lrow;
        float sfr[4];
#pragma unroll
        for (int r = 0; r < 4; r++) sfr[r] = __shfl(linv, 4 * g + r);
#pragma unroll
        for (int r = 0; r < 4; r++) {
            int qr = q0 + w * 16 + 4 * g + r;
            unsigned short* orow = aout + (size_t)(b * TT + qr) * DD + h * 64;
#pragma unroll
            for (int nb = 0; nb < 4; nb++)
                orow[nb * 16 + l15] = f2h(accO[nb][r] * sfr[r]);
        }
    }
#undef LOADKV
}

// ---------------------------------------------------------------------------
extern "C" void kernel_launch(void* const* d_in, const int* in_sizes, int n_in,
                              void* d_out, int out_size, void* d_ws, size_t ws_size,
                              hipStream_t stream)
{
    const float* x  = (const float*)d_in[0];
    const float* Wq = (const float*)d_in[1];
    const float* bq = (const float*)d_in[2];
    const float* Wk = (const float*)d_in[3];
    const float* bk = (const float*)d_in[4];
    const float* Wv = (const float*)d_in[5];
    const float* bv = (const float*)d_in[6];
    const float* Wo = (const float*)d_in[7];
    const float* bo = (const float*)d_in[8];
    float* out = (float*)d_out;                     // FLOAT32 output [B,T,D]

    const size_t NE = (size_t)BB * HH * TT * HD;    // 8388608 elements
    // ws: q|k|v f16 contiguous. Direct mode (ws >= 67.1 MB): att f16 at
    // ws[3NE..4NE); Wo_h in dead q region; gemm_h -> d_out (no memcpy).
    // Fallback: att in d_out scratch, Wo_h in d_out after tab, gemm_h -> ws
    // res + memcpy (verified R6 structure).
    unsigned short* qkv  = (unsigned short*)d_ws;
    unsigned short* qb   = qkv;
    unsigned short* kbuf = qkv + NE;
    unsigned short* vbuf = qkv + 2 * NE;
    float* res = (float*)d_ws;                      // overlays dead q+k (fallback)

    // d_out scratch (all dead before the final result lands):
    //  elements [0 .. 8388608)         x_h f16 (fallback: att_h overlays)
    //  elements [8388608 .. 11534336)  wq|wk|wv f16
    //  elements [11534336 .. 11796480) rope table float2 [2048][32]
    //  elements [11796480 .. 12845056) Wo_h f16 (FALLBACK only)
    unsigned short* ds  = (unsigned short*)d_out;
    unsigned short* xh  = ds;
    unsigned short* wh  = ds + 8388608;
    float2* tab = (float2*)(ds + 11534336);

    const bool direct = ws_size >= (size_t)8 * NE;  // bytes: 4 f16 regions
    unsigned short* att = direct ? (qkv + 3 * NE) : ds;
    unsigned short* woh = direct ? (unsigned short*)d_ws : (ds + 11796480);
    float* resout = direct ? out : res;

    const int N = BB * TT;                          // 8192 tokens
    dim3 blk(256);

    // 1) convert x + Wq|Wk|Wv to f16, build rope table (single launch)
    conv_all<<<11520, blk, 0, stream>>>(
        (const float4*)x, (const float4*)Wq, (const float4*)Wk,
        (const float4*)Wv, (ushort4*)xh, (ushort4*)wh, tab);

    // 2) fused QKV projection + table RoPE (single launch, XCD-swizzled)
    gemm_qkv<<<1536, blk, 0, stream>>>(xh, wh, bq, bk, bv, tab, qkv);

    // 3) flash attention (8-wave QBLK=128) -> att f16
    attn_mfma<<<dim3(8, HH, BB), dim3(512), 0, stream>>>(qb, kbuf, vbuf, att);

    // 4) convert Wo AFTER attn into a region gemm_h never writes
    conv_wo<<<1024, blk, 0, stream>>>((const float4*)Wo, (ushort4*)woh);

    // 5) O-projection -> f32 (direct: into d_out; fallback: ws res)
    gemm_h<<<dim3(DD / 128, N / 128), blk, 0, stream>>>(att, woh, bo, resout, N, DD, DD);

    // 6) fallback copy
    if (!direct)
        hipMemcpyAsync(out, res, (size_t)N * DD * sizeof(float),
                       hipMemcpyDeviceToDevice, stream);
}